// Round 14
// baseline (257.637 us; speedup 1.0000x reference)
//
#include <hip/hip_runtime.h>

#define NN 20000
#define EE 20000

typedef __attribute__((ext_vector_type(8))) short short8;
typedef __attribute__((ext_vector_type(4))) float f32x4;

// workspace layout (float indices)
#define WS_EFB    0                         // edge_feat bf16 [E][64] = 640000 f32 units
#define WS_TRANS  640000                    // trans f32 [E][3]
#define WS_CNTI   700000                    // int cnt[N]
#define WS_OFF    720000                    // int off[N+1]
#define WS_CUR    740001                    // int cursor[N]
#define WS_EIDX   760001                    // int eidx[E]
#define WS_CORE_END 780001
#define WS_AL     ((WS_CORE_END + 3) & ~3)
#define WS1S_ELEMS (4096*128)               // bf16: swizzled 64*Ws1 (1 MB)
// MLP weight fragment buffers (bf16 elems)
#define FB_WE1 0        // K=129->160, 5 steps : 10240
#define FB_WE2 10240    // K=64, 2 steps       : 4096
#define FB_WS2 14336    // K=128, 4 steps      : 8192
#define FB_WC1 22528    // K=64, 2 steps       : 4096
#define FB_WN1 26624    // K=131->160, 5 steps : 10240
#define FB_WN2 36864    // K=64, 2 steps, 5 tn : 5120
#define FB_ELEMS 41984

// edge-kernel LDS (f32 indices) — 80-edge / 1024-thread blocks
// R0 [0,10240): A_in bf16 [80][336B]=6720 ; partial-acc dump 10240 ; T1A bf16 [80][272B]=5440
#define AIN_B   0
#define T1A_B   0
#define E1A_F   10240    // e1 / ef bf16 A-form [80][144B] = 2880 f32
#define GF32_F  13120    // g f32 [64 i][88] ; later v f32 = 5632
#define GA_F    18752    // g bf16 A-form [80][144B] = 2880 f32
#define SM_FLOATS 21632  // 86.5 KB (1 block/CU)
#define E1A_B   (E1A_F*4)
#define EFA_B   (E1A_F*4)
#define GA_B    (GA_F*4)

// node-kernel LDS (f32 indices)
#define NMA_B   0        // m bf16 [32][336B] = 2688 f32
#define NHP_F   2688     // h_pos f32 [32][68] = 2176
#define NW1_F   4864     // Wn1 frags 10240 bf16 = 5120 f32
#define NW2_F   9984     // Wn2 frags 5120 bf16 = 2560 f32
#define NZA_F   12544    // z bf16 A-form [32][144B] = 1152 f32
#define NSM_FLOATS 13696 // 54.8 KB
#define NW1_B   (NW1_F*4)
#define NW2_B   (NW2_F*4)
#define NZA_B   (NZA_F*4)

__device__ __forceinline__ float siluf(float x) {
    return x * (1.0f / (1.0f + __expf(-x)));
}
__device__ __forceinline__ unsigned short f2bf(float f) {
    union { float f; unsigned u; } v; v.f = f;
    return (unsigned short)((v.u + 0x7FFF + ((v.u >> 16) & 1)) >> 16);
}
__device__ __forceinline__ float bf2f(unsigned short x) {
    union { unsigned u; float f; } v; v.u = ((unsigned)x) << 16; return v.f;
}

// ---------- CSR scan (fill is fused into the edge kernel) ----------
__global__ void scan_csr(const int* __restrict__ cnt, int* __restrict__ off,
                         int* __restrict__ cursor) {
    const int t = threadIdx.x;        // 1024 threads, 20 items each
    __shared__ int ps[1024];
    int loc[20];
    int s = 0;
    const int base = t * 20;
    #pragma unroll
    for (int k = 0; k < 20; ++k) {
        const int i = base + k;
        const int c = (i < NN) ? cnt[i] : 0;
        loc[k] = s; s += c;
    }
    ps[t] = s;
    __syncthreads();
    for (int d = 1; d < 1024; d <<= 1) {
        const int v = (t >= d) ? ps[t - d] : 0;
        __syncthreads();
        ps[t] += v;
        __syncthreads();
    }
    const int excl = ps[t] - s;
    #pragma unroll
    for (int k = 0; k < 20; ++k) {
        const int i = base + k;
        if (i < NN) { const int v = excl + loc[k]; off[i] = v; cursor[i] = v; }
    }
    if (t == 1023) off[NN] = ps[1023];
}

// ---------- combined prep: SO3 B swizzle + all MLP frag buffers + degree histogram ----------
__global__ void prep_all(const float* __restrict__ Ws1,
                         const float* __restrict__ We1, const float* __restrict__ We2,
                         const float* __restrict__ Ws2, const float* __restrict__ Wc1,
                         const float* __restrict__ Wn1, const float* __restrict__ Wn2,
                         unsigned short* __restrict__ ws1s, unsigned short* __restrict__ fbb,
                         const int* __restrict__ ei, int* __restrict__ cnt)
{
    const int b = blockIdx.x, t = threadIdx.x;
    if (b < 256) {
        // ws1s[((s*8+tn)*64 + l)*8 + u] = bf16(64*Ws1[(s*32 + 8*(l>>4) + u)][tn*16 + (l&15)])
        const int tid = b * 256 + t;
        const int l = tid & 63, fid = tid >> 6;
        const int s = fid >> 3, tn = fid & 7;
        const int krow = s * 32 + 8 * (l >> 4);
        const int ncol = tn * 16 + (l & 15);
        short8 frag;
        #pragma unroll
        for (int u = 0; u < 8; ++u)
            frag[u] = (short)f2bf(64.0f * Ws1[(krow + u) * 128 + ncol]);
        *(short8*)&ws1s[(size_t)tid * 8] = frag;
    } else if (b < 277) {
        const int idx = (b - 256) * 256 + t;   // 0..5375, valid < 5248
        if (idx < 5248) {
            const float* W; int K, NC, NTN; unsigned short* dst; int local;
            if (idx < 1280)      { W = We1; K = 129; NC = 64; NTN = 4; dst = fbb + FB_WE1; local = idx; }
            else if (idx < 1792) { W = We2; K = 64;  NC = 64; NTN = 4; dst = fbb + FB_WE2; local = idx - 1280; }
            else if (idx < 2816) { W = Ws2; K = 128; NC = 64; NTN = 4; dst = fbb + FB_WS2; local = idx - 1792; }
            else if (idx < 3328) { W = Wc1; K = 64;  NC = 64; NTN = 4; dst = fbb + FB_WC1; local = idx - 2816; }
            else if (idx < 4608) { W = Wn1; K = 131; NC = 64; NTN = 4; dst = fbb + FB_WN1; local = idx - 3328; }
            else                 { W = Wn2; K = 64;  NC = 67; NTN = 5; dst = fbb + FB_WN2; local = idx - 4608; }
            const int per = NTN * 64;
            const int s = local / per, rem = local % per, tn = rem >> 6, ll = rem & 63;
            const int ccol = tn * 16 + (ll & 15), kr0 = s * 32 + 8 * (ll >> 4);
            short8 frag;
            #pragma unroll
            for (int u = 0; u < 8; ++u) {
                const int kr = kr0 + u;
                frag[u] = (kr < K && ccol < NC) ? (short)f2bf(W[kr * NC + ccol]) : (short)0;
            }
            *(short8*)&dst[local * 8] = frag;
        }
    } else {
        const int e = (b - 277) * 256 + t;
        if (e < EE) atomicAdd(&cnt[ei[e]], 1);
    }
}

// 80 edges/block, 1024 threads (16 waves), grid = 250 <= 256 CUs (no tail).
// GEMM: wave pair (ctile, ihalf) i-splits the K-stream -> 64 KB/wave (was 128).
// __launch_bounds__(1024, 4): 1024-thr block = 4 waves/EU -> VGPR cap 512/4 = 128.
__global__ __launch_bounds__(1024, 4)
void egcl_edge_kernel(const float* __restrict__ h, const float* __restrict__ coord,
                      const int* __restrict__ ei,
                      const unsigned short* __restrict__ fb,
                      const float* __restrict__ be1, const float* __restrict__ be2,
                      const unsigned short* __restrict__ Ws1s, const float* __restrict__ bs1,
                      const float* __restrict__ bs2, const float* __restrict__ bc1,
                      const float* __restrict__ Wc2,
                      int* __restrict__ cur, int* __restrict__ eidx,
                      unsigned short* __restrict__ efb_out, float* __restrict__ trans_out)
{
    __shared__ __attribute__((aligned(16))) float sm[SM_FLOATS];
    __shared__ int s_row[80], s_col[80];
    __shared__ float s_cd[240], s_rad[80];

    const int t = threadIdx.x;
    const int e0 = blockIdx.x * 80;    // 250 * 80 == 20000 exactly
    const int l = t & 63, w = t >> 6;  // 16 waves
    const int kg = l >> 4;
    const int akoff = kg * 16;

    if (t < 80) {
        const int eid = e0 + t;
        const int r = ei[eid], c = ei[EE + eid];
        s_row[t] = r; s_col[t] = c;
        const float dx = coord[r*3+0] - coord[c*3+0];
        const float dy = coord[r*3+1] - coord[c*3+1];
        const float dz = coord[r*3+2] - coord[c*3+2];
        s_cd[t] = dx; s_cd[80+t] = dy; s_cd[160+t] = dz;
        s_rad[t] = dx*dx + dy*dy + dz*dz;
        // fused CSR fill (scan_csr ran before this kernel; node runs after)
        const int p = atomicAdd(&cur[r], 1);
        eidx[p] = eid;
    }
    __syncthreads();

    // P1: gather A_in bf16 [80 e][160k pad->336B] = [h_row(64), h_col(64), radial, 0]
    {
        const int ee = t >> 3, fg8 = t & 7;
        if (ee < 80) {
            const int r = s_row[ee], c = s_col[ee];
            short8 fr, fc;
            #pragma unroll
            for (int u = 0; u < 8; ++u) fr[u] = (short)f2bf(h[(size_t)r*64 + fg8*8 + u]);
            #pragma unroll
            for (int u = 0; u < 8; ++u) fc[u] = (short)f2bf(h[(size_t)c*64 + fg8*8 + u]);
            *(short8*)((char*)sm + AIN_B + ee*336 + fg8*16)     = fr;
            *(short8*)((char*)sm + AIN_B + ee*336 + (8+fg8)*16) = fc;
            if (fg8 < 5) {
                short8 z = {0,0,0,0,0,0,0,0};
                if (fg8 == 0) z[0] = (short)f2bf(s_rad[ee]);
                *(short8*)((char*)sm + AIN_B + ee*336 + (16 + fg8)*16) = z;
            }
        }
    }
    __syncthreads();

    // P2: e1 = silu(in @ We1 + be1) (MFMA, K=160) -> E1A bf16. 20 tiles (5 mr x 4 tn).
    for (int tile = w; tile < 20; tile += 16) {
        const int mr = tile >> 2, tn = tile & 3;
        const int ar = mr*16 + (l & 15), orw = mr*16 + (kg << 2), col = tn*16 + (l & 15);
        const short8* Bf = (const short8*)(fb + FB_WE1);
        f32x4 acc = {0.f, 0.f, 0.f, 0.f};
        #pragma unroll
        for (int s = 0; s < 5; ++s) {
            const short8 a = *(const short8*)((const char*)sm + AIN_B + ar*336 + s*64 + akoff);
            acc = __builtin_amdgcn_mfma_f32_16x16x32_bf16(a, Bf[(s*4 + tn)*64 + l], acc, 0, 0, 0);
        }
        const float bb = be1[col];
        #pragma unroll
        for (int r = 0; r < 4; ++r)
            *(unsigned short*)((char*)sm + E1A_B + (orw + r)*144 + col*2)
                = f2bf(siluf(acc[r] + bb));
    }
    __syncthreads();

    // P3: g = silu(e1 @ We2 + be2) (MFMA, K=64) -> GF32 f32 [i][88] + GA bf16 A-form
    for (int tile = w; tile < 20; tile += 16) {
        const int mr = tile >> 2, tn = tile & 3;
        const int ar = mr*16 + (l & 15), orw = mr*16 + (kg << 2), col = tn*16 + (l & 15);
        const short8* Bf = (const short8*)(fb + FB_WE2);
        f32x4 acc = {0.f, 0.f, 0.f, 0.f};
        #pragma unroll
        for (int s = 0; s < 2; ++s) {
            const short8 a = *(const short8*)((const char*)sm + E1A_B + ar*144 + s*64 + akoff);
            acc = __builtin_amdgcn_mfma_f32_16x16x32_bf16(a, Bf[(s*4 + tn)*64 + l], acc, 0, 0, 0);
        }
        const float bb = be2[col];
        #pragma unroll
        for (int r = 0; r < 4; ++r) {
            const float sv = siluf(acc[r] + bb);
            sm[GF32_F + col*88 + orw + r] = sv;
            *(unsigned short*)((char*)sm + GA_B + (orw + r)*144 + col*2) = f2bf(sv);
        }
    }
    __syncthreads();

    // P4: SO3 GEMM acc[e,k] = sum_i g[e,i]*(g_bf16[e,:] @ 64*Ws1_i[:,k])
    // Wave (ctile = w&7, ih = w>>3): cols [ctile*16,+16) x 80 edges, i in [32*ih,+32).
    // B: L2 -> registers, 2 banks x 4 steps, compiler-counted vmcnt, no barriers.
    const int ctile = w & 7, ih = w >> 3;

    short8 A[5][2];
    #pragma unroll
    for (int et = 0; et < 5; ++et)
        #pragma unroll
        for (int kh = 0; kh < 2; ++kh)
            A[et][kh] = *(const short8*)((const char*)sm + GA_B +
                                         (et*16 + (l & 15))*144 + kh*64 + kg*16);

    f32x4 accv[5];
    #pragma unroll
    for (int et = 0; et < 5; ++et) accv[et] = (f32x4){0.f, 0.f, 0.f, 0.f};

    {
        const short8* Bp = (const short8*)Ws1s;   // frag for step s: Bp[(s*8 + ct)*64 + l]
        short8 q0[4], q1[4];

#define LOADBANK(P, G) { \
    _Pragma("unroll") \
    for (int j = 0; j < 4; ++j) P[j] = Bp[(((64*ih + (G)*4 + j)*8 + ctile)*64 + l)]; \
    __builtin_amdgcn_sched_barrier(0); }
#define USEBANK(P, G) { \
    _Pragma("unroll") \
    for (int ii = 0; ii < 2; ++ii) { \
        const int i_ = 32*ih + 2*(G) + ii; \
        _Pragma("unroll") \
        for (int et = 0; et < 5; ++et) { \
            f32x4 c = __builtin_amdgcn_mfma_f32_16x16x32_bf16(A[et][0], P[2*ii], (f32x4){0.f,0.f,0.f,0.f}, 0, 0, 0); \
            c = __builtin_amdgcn_mfma_f32_16x16x32_bf16(A[et][1], P[2*ii+1], c, 0, 0, 0); \
            const f32x4 g4 = *(const f32x4*)&sm[GF32_F + i_*88 + et*16 + (kg << 2)]; \
            _Pragma("unroll") \
            for (int r = 0; r < 4; ++r) accv[et][r] = fmaf(g4[r], c[r], accv[et][r]); \
        } \
    } }

        LOADBANK(q0, 0)
        LOADBANK(q1, 1)
        #pragma unroll 1
        for (int m = 0; m < 7; ++m) {
            USEBANK(q0, 2*m)     LOADBANK(q0, 2*m + 2)
            USEBANK(q1, 2*m + 1) LOADBANK(q1, 2*m + 3)
        }
        USEBANK(q0, 14)
        USEBANK(q1, 15)
#undef LOADBANK
#undef USEBANK
    }

    // pair-reduce: waves 8-15 dump partials into dead AIN region; waves 0-7 add.
    if (w >= 8) {
        const int base = ((w - 8)*64 + l)*20;
        #pragma unroll
        for (int et = 0; et < 5; ++et) *(f32x4*)&sm[base + et*4] = accv[et];
    }
    __syncthreads();
    if (w < 8) {
        const int base = (w*64 + l)*20;
        #pragma unroll
        for (int et = 0; et < 5; ++et) {
            const f32x4 p = *(const f32x4*)&sm[base + et*4];
            #pragma unroll
            for (int r = 0; r < 4; ++r) accv[et][r] += p[r];
        }
    }
    __syncthreads();   // all partial reads done; region reusable for t1

    // t1 = relu(acc + bs1) -> T1A bf16 A-form [80 e][128 k]  (waves 0-7 only)
    if (w < 8) {
        const int kcol = ctile*16 + (l & 15);
        const float bk = bs1[kcol];
        #pragma unroll
        for (int et = 0; et < 5; ++et)
            #pragma unroll
            for (int r = 0; r < 4; ++r)
                *(unsigned short*)((char*)sm + T1A_B + (et*16 + (kg<<2) + r)*272 + kcol*2)
                    = f2bf(fmaxf(accv[et][r] + bk, 0.0f));
    }
    __syncthreads();

    // P5: ef = t1 @ Ws2 + bs2 (MFMA, K=128) -> global efb (bf16) + EFA bf16
    for (int tile = w; tile < 20; tile += 16) {
        const int mr = tile >> 2, tn = tile & 3;
        const int ar = mr*16 + (l & 15), orw = mr*16 + (kg << 2), col = tn*16 + (l & 15);
        const short8* Bf = (const short8*)(fb + FB_WS2);
        f32x4 acc = {0.f, 0.f, 0.f, 0.f};
        #pragma unroll
        for (int s = 0; s < 4; ++s) {
            const short8 a = *(const short8*)((const char*)sm + T1A_B + ar*272 + s*64 + akoff);
            acc = __builtin_amdgcn_mfma_f32_16x16x32_bf16(a, Bf[(s*4 + tn)*64 + l], acc, 0, 0, 0);
        }
        const float bb = bs2[col];
        #pragma unroll
        for (int r = 0; r < 4; ++r) {
            const unsigned short bv = f2bf(acc[r] + bb);
            efb_out[(size_t)(e0 + orw + r)*64 + col] = bv;
            *(unsigned short*)((char*)sm + EFA_B + (orw + r)*144 + col*2) = bv;
        }
    }
    __syncthreads();

    // P6: v = silu(ef @ Wc1 + bc1) (MFMA, K=64) -> V f32 (over dead GF32)
    for (int tile = w; tile < 20; tile += 16) {
        const int mr = tile >> 2, tn = tile & 3;
        const int ar = mr*16 + (l & 15), orw = mr*16 + (kg << 2), col = tn*16 + (l & 15);
        const short8* Bf = (const short8*)(fb + FB_WC1);
        f32x4 acc = {0.f, 0.f, 0.f, 0.f};
        #pragma unroll
        for (int s = 0; s < 2; ++s) {
            const short8 a = *(const short8*)((const char*)sm + EFA_B + ar*144 + s*64 + akoff);
            acc = __builtin_amdgcn_mfma_f32_16x16x32_bf16(a, Bf[(s*4 + tn)*64 + l], acc, 0, 0, 0);
        }
        const float bb = bc1[col];
        #pragma unroll
        for (int r = 0; r < 4; ++r)
            sm[GF32_F + col*88 + orw + r] = siluf(acc[r] + bb);
    }
    __syncthreads();

    // P7: cw = v . Wc2 -> trans
    if (t < 80) {
        float cw = 0.0f;
        for (int f = 0; f < 64; ++f) cw = fmaf(sm[GF32_F + f*88 + t], Wc2[f], cw);
        const int eid = e0 + t;
        trans_out[eid*3 + 0] = s_cd[t]     * cw;
        trans_out[eid*3 + 1] = s_cd[80+t]  * cw;
        trans_out[eid*3 + 2] = s_cd[160+t] * cw;
    }
}

__global__ __launch_bounds__(512, 2)
void egcl_node_kernel(const float* __restrict__ h, const float* __restrict__ coord,
                      const int* __restrict__ ei,
                      const unsigned short* __restrict__ fb,
                      const float* __restrict__ bn1, const float* __restrict__ bn2,
                      const unsigned short* __restrict__ efb, const float* __restrict__ trans,
                      const int* __restrict__ off, const int* __restrict__ eidx,
                      float* __restrict__ out)
{
    __shared__ __attribute__((aligned(16))) float smn[NSM_FLOATS];
    const int t = threadIdx.x;
    const int n0 = blockIdx.x * 32;
    const int l = t & 63, w = t >> 6;
    const int mt = w & 1, tn4 = w >> 1;
    const int kg = l >> 4;
    const int arow = mt * 16 + (l & 15);
    const int akoff = kg * 16;
    const int orow = mt * 16 + (kg << 2);
    const int col = tn4 * 16 + (l & 15);

    // stage Wn1 + Wn2 frags
    for (int i = t*8; i < 10240; i += 4096)
        *(f32x4*)&smn[NW1_F + (i >> 1)] = *(const f32x4*)&fb[FB_WN1 + i];
    for (int i = t*8; i < 5120; i += 4096)
        *(f32x4*)&smn[NW2_F + (i >> 1)] = *(const f32x4*)&fb[FB_WN2 + i];

    // N1 gather: m = [h(64), rel(3), agg(64), 0-pad] bf16 A-form + h_pos f32
    {
        const int nd = t >> 4, fg = t & 15;
        const int gn = n0 + nd;
        const f32x4 hv = *(const f32x4*)&h[(size_t)gn*64 + fg*4];
        #pragma unroll
        for (int u = 0; u < 4; ++u) {
            smn[NHP_F + nd*68 + fg*4 + u] = hv[u];
            *(unsigned short*)((char*)smn + NMA_B + nd*336 + (fg*4+u)*2) = f2bf(hv[u]);
        }
        const int o0 = off[gn], o1 = off[gn + 1];
        float acc[4] = {0.f, 0.f, 0.f, 0.f};
        for (int j = o0; j < o1; ++j) {
            const int e2 = eidx[j];
            const unsigned short* ep = &efb[(size_t)e2*64 + fg*4];
            #pragma unroll
            for (int u = 0; u < 4; ++u) acc[u] += bf2f(ep[u]);
        }
        #pragma unroll
        for (int u = 0; u < 4; ++u)
            *(unsigned short*)((char*)smn + NMA_B + nd*336 + (67+fg*4+u)*2) = f2bf(acc[u]);
    }
    if (t < 32) {
        const int gn = n0 + t;
        const int r = ei[gn], c = ei[EE + gn];   // rel for node n comes from edge n (E==N)
        const float dx = coord[r*3+0] - coord[c*3+0];
        const float dy = coord[r*3+1] - coord[c*3+1];
        const float dz = coord[r*3+2] - coord[c*3+2];
        const float inv = 1.0f / (sqrtf(dx*dx + dy*dy + dz*dz) + 1e-8f);
        const float rl[3] = {dx*inv, dy*inv, dz*inv};
        #pragma unroll
        for (int k = 0; k < 3; ++k) {
            smn[NHP_F + t*68 + 64 + k] = rl[k];
            *(unsigned short*)((char*)smn + NMA_B + t*336 + (64+k)*2) = f2bf(rl[k]);
        }
        #pragma unroll
        for (int cz = 131; cz < 136; ++cz)
            *(unsigned short*)((char*)smn + NMA_B + t*336 + cz*2) = 0;
        const short8 z8 = {0,0,0,0,0,0,0,0};
        #pragma unroll
        for (int ch = 17; ch < 20; ++ch)
            *(short8*)((char*)smn + NMA_B + t*336 + ch*16) = z8;
        const int o0 = off[gn], o1 = off[gn + 1];
        float nx = 0.f, ny = 0.f, nz = 0.f;
        for (int j = o0; j < o1; ++j) {
            const int e2 = eidx[j];
            nx += trans[e2*3 + 0];
            ny += trans[e2*3 + 1];
            nz += trans[e2*3 + 2];
        }
        const float cnt = fmaxf((float)(o1 - o0), 1.0f);
        out[NN*67 + gn*3 + 0] = coord[gn*3 + 0] + nx / cnt;
        out[NN*67 + gn*3 + 1] = coord[gn*3 + 1] + ny / cnt;
        out[NN*67 + gn*3 + 2] = coord[gn*3 + 2] + nz / cnt;
    }
    __syncthreads();

    // N2: z = silu(m @ Wn1 + bn1) (MFMA, K=160) -> NZA bf16
    {
        f32x4 acc = {0.f, 0.f, 0.f, 0.f};
        #pragma unroll
        for (int s = 0; s < 5; ++s) {
            const short8 a = *(const short8*)((const char*)smn + NMA_B + arow*336 + s*64 + akoff);
            const short8 b = *(const short8*)((const char*)smn + NW1_B + ((s*4 + tn4)*64 + l)*16);
            acc = __builtin_amdgcn_mfma_f32_16x16x32_bf16(a, b, acc, 0, 0, 0);
        }
        const float bb = bn1[col];
        #pragma unroll
        for (int r = 0; r < 4; ++r)
            *(unsigned short*)((char*)smn + NZA_B + (orow + r)*144 + col*2)
                = f2bf(siluf(acc[r] + bb));
    }
    __syncthreads();

    // N3: h_out = h_pos + z @ Wn2 + bn2  (10 tiles of 16 cols over 8 waves)
    for (int tid = w; tid < 10; tid += 8) {
        const int mtN = tid & 1, tnN = tid >> 1;
        f32x4 acc = {0.f, 0.f, 0.f, 0.f};
        #pragma unroll
        for (int s = 0; s < 2; ++s) {
            const short8 a = *(const short8*)((const char*)smn + NZA_B + (mtN*16 + (l & 15))*144 + s*64 + akoff);
            const short8 b = *(const short8*)((const char*)smn + NW2_B + ((s*5 + tnN)*64 + l)*16);
            acc = __builtin_amdgcn_mfma_f32_16x16x32_bf16(a, b, acc, 0, 0, 0);
        }
        const int colN = tnN*16 + (l & 15);
        if (colN < 67) {
            const float bb = bn2[colN];
            #pragma unroll
            for (int r = 0; r < 4; ++r) {
                const int row = mtN*16 + (kg << 2) + r;
                out[(size_t)(n0 + row)*67 + colN] = smn[NHP_F + row*68 + colN] + acc[r] + bb;
            }
        }
    }
}

extern "C" void kernel_launch(void* const* d_in, const int* in_sizes, int n_in,
                              void* d_out, int out_size, void* d_ws, size_t ws_size,
                              hipStream_t stream)
{
    (void)in_sizes; (void)n_in; (void)out_size; (void)ws_size;
    const float* h     = (const float*)d_in[0];
    const float* coord = (const float*)d_in[1];
    const int*   ei    = (const int*)d_in[2];
    const float* We1   = (const float*)d_in[3];
    const float* be1   = (const float*)d_in[4];
    const float* We2   = (const float*)d_in[5];
    const float* be2   = (const float*)d_in[6];
    const float* Ws1   = (const float*)d_in[7];
    const float* bs1   = (const float*)d_in[8];
    const float* Ws2   = (const float*)d_in[9];
    const float* bs2   = (const float*)d_in[10];
    const float* Wc1   = (const float*)d_in[11];
    const float* bc1   = (const float*)d_in[12];
    const float* Wc2   = (const float*)d_in[13];
    const float* Wn1   = (const float*)d_in[14];
    const float* bn1   = (const float*)d_in[15];
    const float* Wn2   = (const float*)d_in[16];
    const float* bn2   = (const float*)d_in[17];
    float* ws  = (float*)d_ws;
    float* out = (float*)d_out;

    unsigned short* efb = (unsigned short*)(ws + WS_EFB);
    float* trans = ws + WS_TRANS;
    int* cnti = (int*)(ws + WS_CNTI);
    int* off  = (int*)(ws + WS_OFF);
    int* cur  = (int*)(ws + WS_CUR);
    int* eidx = (int*)(ws + WS_EIDX);
    unsigned short* ws1s = (unsigned short*)(ws + WS_AL);
    unsigned short* fbb  = ws1s + WS1S_ELEMS;

    hipMemsetAsync((void*)cnti, 0, (size_t)NN * sizeof(int), stream);
    prep_all<<<277 + (EE + 255)/256, 256, 0, stream>>>(Ws1, We1, We2, Ws2, Wc1, Wn1, Wn2,
                                                       ws1s, fbb, ei, cnti);
    scan_csr<<<1, 1024, 0, stream>>>(cnti, off, cur);
    egcl_edge_kernel<<<EE/80, 1024, 0, stream>>>(h, coord, ei, fbb, be1, be2,
                                                 ws1s, bs1, bs2, bc1, Wc2,
                                                 cur, eidx, efb, trans);
    egcl_node_kernel<<<NN/32, 512, 0, stream>>>(h, coord, ei, fbb, bn1, bn2,
                                                efb, trans, off, eidx, out);
}

// Round 15
// 96.961 us; speedup vs baseline: 2.6571x; 2.6571x over previous
//
#include <hip/hip_runtime.h>

#define NN 20000
#define EE 20000

typedef __attribute__((ext_vector_type(8))) short short8;
typedef __attribute__((ext_vector_type(4))) float f32x4;

// workspace layout (float indices)
#define WS_EFB    0                         // edge_feat bf16 [E][64] = 640000 f32 units
#define WS_TRANS  640000                    // trans f32 [E][3]
#define WS_CNTI   700000                    // int cnt[N]
#define WS_OFF    720000                    // int off[N+1]
#define WS_CUR    740001                    // int cursor[N]
#define WS_EIDX   760001                    // int eidx[E]
#define WS_CORE_END 780001
#define WS_AL     ((WS_CORE_END + 3) & ~3)
#define WS1S_ELEMS (4096*128)               // bf16: swizzled 64*Ws1 (1 MB)
// MLP weight fragment buffers (bf16 elems)
#define FB_WE1 0        // K=129->160, 5 steps : 10240
#define FB_WE2 10240    // K=64, 2 steps       : 4096
#define FB_WS2 14336    // K=128, 4 steps      : 8192
#define FB_WC1 22528    // K=64, 2 steps       : 4096
#define FB_WN1 26624    // K=131->160, 5 steps : 10240
#define FB_WN2 36864    // K=64, 2 steps, 5 tn : 5120
#define FB_ELEMS 41984

// edge-kernel LDS (f32 indices) — 64-edge blocks, no weight staging (frags from L2)
#define AIN_F   0        // A_in bf16 [64][336B] = 5376 f32 ; later T1A bf16 [64][272B]
#define E1A_F   5376     // e1 / ef bf16 A-form [64][144B] = 2304 f32
#define GF32_F  7680     // g f32 [64 i][72] (stride 72) ; later v   = 4608 f32
#define GA_F    12288    // g bf16 A-form [64][144B] = 2304 f32
#define SM_FLOATS 14592  // 58.4 KB
#define AIN_B   0
#define T1A_B   0
#define E1A_B   (E1A_F*4)
#define EFA_B   (E1A_F*4)
#define GA_B    (GA_F*4)

// node-kernel LDS (f32 indices)
#define NMA_B   0        // m bf16 [32][336B] = 2688 f32
#define NHP_F   2688     // h_pos f32 [32][68] = 2176
#define NW1_F   4864     // Wn1 frags 10240 bf16 = 5120 f32
#define NW2_F   9984     // Wn2 frags 5120 bf16 = 2560 f32
#define NZA_F   12544    // z bf16 A-form [32][144B] = 1152 f32
#define NSM_FLOATS 13696 // 54.8 KB
#define NW1_B   (NW1_F*4)
#define NW2_B   (NW2_F*4)
#define NZA_B   (NZA_F*4)

__device__ __forceinline__ float siluf(float x) {
    return x * (1.0f / (1.0f + __expf(-x)));
}
__device__ __forceinline__ unsigned short f2bf(float f) {
    union { float f; unsigned u; } v; v.f = f;
    return (unsigned short)((v.u + 0x7FFF + ((v.u >> 16) & 1)) >> 16);
}
__device__ __forceinline__ float bf2f(unsigned short x) {
    union { unsigned u; float f; } v; v.u = ((unsigned)x) << 16; return v.f;
}

// ---------- CSR scan (fill is fused into the edge kernel) ----------
__global__ void scan_csr(const int* __restrict__ cnt, int* __restrict__ off,
                         int* __restrict__ cursor) {
    const int t = threadIdx.x;        // 1024 threads, 20 items each
    __shared__ int ps[1024];
    int loc[20];
    int s = 0;
    const int base = t * 20;
    #pragma unroll
    for (int k = 0; k < 20; ++k) {
        const int i = base + k;
        const int c = (i < NN) ? cnt[i] : 0;
        loc[k] = s; s += c;
    }
    ps[t] = s;
    __syncthreads();
    for (int d = 1; d < 1024; d <<= 1) {
        const int v = (t >= d) ? ps[t - d] : 0;
        __syncthreads();
        ps[t] += v;
        __syncthreads();
    }
    const int excl = ps[t] - s;
    #pragma unroll
    for (int k = 0; k < 20; ++k) {
        const int i = base + k;
        if (i < NN) { const int v = excl + loc[k]; off[i] = v; cursor[i] = v; }
    }
    if (t == 1023) off[NN] = ps[1023];
}

// ---------- combined prep: SO3 B swizzle + all MLP frag buffers + degree histogram ----------
__global__ void prep_all(const float* __restrict__ Ws1,
                         const float* __restrict__ We1, const float* __restrict__ We2,
                         const float* __restrict__ Ws2, const float* __restrict__ Wc1,
                         const float* __restrict__ Wn1, const float* __restrict__ Wn2,
                         unsigned short* __restrict__ ws1s, unsigned short* __restrict__ fbb,
                         const int* __restrict__ ei, int* __restrict__ cnt)
{
    const int b = blockIdx.x, t = threadIdx.x;
    if (b < 256) {
        // ws1s[((s*8+tn)*64 + l)*8 + u] = bf16(64*Ws1[(s*32 + 8*(l>>4) + u)][tn*16 + (l&15)])
        const int tid = b * 256 + t;
        const int l = tid & 63, fid = tid >> 6;
        const int s = fid >> 3, tn = fid & 7;
        const int krow = s * 32 + 8 * (l >> 4);
        const int ncol = tn * 16 + (l & 15);
        short8 frag;
        #pragma unroll
        for (int u = 0; u < 8; ++u)
            frag[u] = (short)f2bf(64.0f * Ws1[(krow + u) * 128 + ncol]);
        *(short8*)&ws1s[(size_t)tid * 8] = frag;
    } else if (b < 277) {
        const int idx = (b - 256) * 256 + t;   // 0..5375, valid < 5248
        if (idx < 5248) {
            const float* W; int K, NC, NTN; unsigned short* dst; int local;
            if (idx < 1280)      { W = We1; K = 129; NC = 64; NTN = 4; dst = fbb + FB_WE1; local = idx; }
            else if (idx < 1792) { W = We2; K = 64;  NC = 64; NTN = 4; dst = fbb + FB_WE2; local = idx - 1280; }
            else if (idx < 2816) { W = Ws2; K = 128; NC = 64; NTN = 4; dst = fbb + FB_WS2; local = idx - 1792; }
            else if (idx < 3328) { W = Wc1; K = 64;  NC = 64; NTN = 4; dst = fbb + FB_WC1; local = idx - 2816; }
            else if (idx < 4608) { W = Wn1; K = 131; NC = 64; NTN = 4; dst = fbb + FB_WN1; local = idx - 3328; }
            else                 { W = Wn2; K = 64;  NC = 67; NTN = 5; dst = fbb + FB_WN2; local = idx - 4608; }
            const int per = NTN * 64;
            const int s = local / per, rem = local % per, tn = rem >> 6, ll = rem & 63;
            const int ccol = tn * 16 + (ll & 15), kr0 = s * 32 + 8 * (ll >> 4);
            short8 frag;
            #pragma unroll
            for (int u = 0; u < 8; ++u) {
                const int kr = kr0 + u;
                frag[u] = (kr < K && ccol < NC) ? (short)f2bf(W[kr * NC + ccol]) : (short)0;
            }
            *(short8*)&dst[local * 8] = frag;
        }
    } else {
        const int e = (b - 277) * 256 + t;
        if (e < EE) atomicAdd(&cnt[ei[e]], 1);
    }
}

// 64 edges/block, 512 threads. __launch_bounds__(512, 2) is the ONLY pair the
// allocator has honored with a ~110-reg budget (R8/R13: VGPR 104-116, no spill);
// (512,4) and (1024,4) both flipped to the 64-reg bucket and spilled ~500 MB.
__global__ __launch_bounds__(512, 2)
void egcl_edge_kernel(const float* __restrict__ h, const float* __restrict__ coord,
                      const int* __restrict__ ei,
                      const unsigned short* __restrict__ fb,
                      const float* __restrict__ be1, const float* __restrict__ be2,
                      const unsigned short* __restrict__ Ws1s, const float* __restrict__ bs1,
                      const float* __restrict__ bs2, const float* __restrict__ bc1,
                      const float* __restrict__ Wc2,
                      int* __restrict__ cur, int* __restrict__ eidx,
                      unsigned short* __restrict__ efb_out, float* __restrict__ trans_out)
{
    __shared__ __attribute__((aligned(16))) float sm[SM_FLOATS];
    __shared__ int s_row[64], s_col[64];
    __shared__ float s_cd[192], s_rad[64];

    const int t = threadIdx.x;
    const int e0 = blockIdx.x * 64;    // 313 blocks; last block: 48 valid edges
    const int l = t & 63, w = t >> 6;
    const int kg = l >> 4;
    const int akoff = kg * 16;
    // MLP tiling: wave w owns row-tile (w&3), col-tiles (w>>2) and (w>>2)+2
    const int mrow = (w & 3) * 16;
    const int arow = mrow + (l & 15);
    const int orow = mrow + (kg << 2);
    const int cA = w >> 2;

    if (t < 64) {
        const int eid = min(e0 + t, EE - 1);
        const int r = ei[eid], c = ei[EE + eid];
        s_row[t] = r; s_col[t] = c;
        const float dx = coord[r*3+0] - coord[c*3+0];
        const float dy = coord[r*3+1] - coord[c*3+1];
        const float dz = coord[r*3+2] - coord[c*3+2];
        s_cd[t] = dx; s_cd[64+t] = dy; s_cd[128+t] = dz;
        s_rad[t] = dx*dx + dy*dy + dz*dz;
        // fused CSR fill (scan_csr ran before this kernel; node runs after)
        if (e0 + t < EE) {
            const int p = atomicAdd(&cur[r], 1);
            eidx[p] = e0 + t;
        }
    }
    __syncthreads();

    // P1: gather A_in bf16 [64 e][160k pad->336B] = [h_row(64), h_col(64), radial, 0]
    {
        const int ee = t >> 3, fg8 = t & 7;
        const int r = s_row[ee], c = s_col[ee];
        short8 fr, fc;
        #pragma unroll
        for (int u = 0; u < 8; ++u) fr[u] = (short)f2bf(h[(size_t)r*64 + fg8*8 + u]);
        #pragma unroll
        for (int u = 0; u < 8; ++u) fc[u] = (short)f2bf(h[(size_t)c*64 + fg8*8 + u]);
        *(short8*)((char*)sm + AIN_B + ee*336 + fg8*16)       = fr;
        *(short8*)((char*)sm + AIN_B + ee*336 + (8+fg8)*16)   = fc;
        if (fg8 < 5) {
            short8 z = {0,0,0,0,0,0,0,0};
            if (fg8 == 0) z[0] = (short)f2bf(s_rad[ee]);
            *(short8*)((char*)sm + AIN_B + ee*336 + (16 + fg8)*16) = z;
        }
    }
    __syncthreads();

    // P2: e1 = silu(in @ We1 + be1) (MFMA, K=160; B-frags direct from L2) -> E1A bf16
    {
        short8 a2[5];
        #pragma unroll
        for (int s = 0; s < 5; ++s)
            a2[s] = *(const short8*)((const char*)sm + AIN_B + arow*336 + s*64 + akoff);
        const short8* Bf = (const short8*)(fb + FB_WE1);
        #pragma unroll
        for (int tt = 0; tt < 2; ++tt) {
            const int tn = cA + tt*2;
            f32x4 acc = {0.f, 0.f, 0.f, 0.f};
            #pragma unroll
            for (int s = 0; s < 5; ++s)
                acc = __builtin_amdgcn_mfma_f32_16x16x32_bf16(a2[s], Bf[(s*4 + tn)*64 + l], acc, 0, 0, 0);
            const int col = tn*16 + (l & 15);
            const float bb = be1[col];
            #pragma unroll
            for (int r = 0; r < 4; ++r)
                *(unsigned short*)((char*)sm + E1A_B + (orow + r)*144 + col*2)
                    = f2bf(siluf(acc[r] + bb));
        }
    }
    __syncthreads();

    // P3: g = silu(e1 @ We2 + be2) (MFMA, K=64) -> GF32 f32 [i][72] + GA bf16 A-form
    {
        short8 a3[2];
        #pragma unroll
        for (int s = 0; s < 2; ++s)
            a3[s] = *(const short8*)((const char*)sm + E1A_B + arow*144 + s*64 + akoff);
        const short8* Bf = (const short8*)(fb + FB_WE2);
        #pragma unroll
        for (int tt = 0; tt < 2; ++tt) {
            const int tn = cA + tt*2;
            f32x4 acc = {0.f, 0.f, 0.f, 0.f};
            #pragma unroll
            for (int s = 0; s < 2; ++s)
                acc = __builtin_amdgcn_mfma_f32_16x16x32_bf16(a3[s], Bf[(s*4 + tn)*64 + l], acc, 0, 0, 0);
            const int col = tn*16 + (l & 15);
            const float bb = be2[col];
            #pragma unroll
            for (int r = 0; r < 4; ++r) {
                const float sv = siluf(acc[r] + bb);
                sm[GF32_F + col*72 + orow + r] = sv;
                *(unsigned short*)((char*)sm + GA_B + (orow + r)*144 + col*2) = f2bf(sv);
            }
        }
    }
    __syncthreads();

    // P4: SO3 GEMM acc[e,k] = sum_i g[e,i]*(g_bf16[e,:] @ 64*Ws1_i[:,k])
    // Wave w owns cols [w*16,+16) x 64 edges (4 et tiles). B: L2 -> registers,
    // 2 banks x 4 steps, compiler-counted vmcnt, zero barriers.
    short8 A[4][2];
    #pragma unroll
    for (int et = 0; et < 4; ++et)
        #pragma unroll
        for (int kh = 0; kh < 2; ++kh)
            A[et][kh] = *(const short8*)((const char*)sm + GA_B +
                                         (et*16 + (l & 15))*144 + kh*64 + kg*16);

    float accv[4][4];
    #pragma unroll
    for (int et = 0; et < 4; ++et)
        #pragma unroll
        for (int r = 0; r < 4; ++r) accv[et][r] = 0.0f;

    {
        const short8* Bp = (const short8*)Ws1s;   // frag for step s: Bp[(s*8 + w)*64 + l]
        short8 q0[4], q1[4];

#define LOADBANK(P, G) { \
    _Pragma("unroll") \
    for (int j = 0; j < 4; ++j) P[j] = Bp[((((G)*4 + j)*8 + w)*64 + l)]; \
    __builtin_amdgcn_sched_barrier(0); }
#define USEBANK(P, G) { \
    _Pragma("unroll") \
    for (int ii = 0; ii < 2; ++ii) { \
        const int i_ = 2*(G) + ii; \
        _Pragma("unroll") \
        for (int et = 0; et < 4; ++et) { \
            f32x4 c = __builtin_amdgcn_mfma_f32_16x16x32_bf16(A[et][0], P[2*ii], (f32x4){0.f,0.f,0.f,0.f}, 0, 0, 0); \
            c = __builtin_amdgcn_mfma_f32_16x16x32_bf16(A[et][1], P[2*ii+1], c, 0, 0, 0); \
            const f32x4 g4 = *(const f32x4*)&sm[GF32_F + i_*72 + et*16 + (kg << 2)]; \
            _Pragma("unroll") \
            for (int r = 0; r < 4; ++r) accv[et][r] = fmaf(g4[r], c[r], accv[et][r]); \
        } \
    } }

        LOADBANK(q0, 0)
        LOADBANK(q1, 1)
        #pragma unroll 1
        for (int m = 0; m < 15; ++m) {
            USEBANK(q0, 2*m)     LOADBANK(q0, 2*m + 2)
            USEBANK(q1, 2*m + 1) LOADBANK(q1, 2*m + 3)
        }
        USEBANK(q0, 30)
        USEBANK(q1, 31)
#undef LOADBANK
#undef USEBANK
    }

    // t1 = relu(acc + bs1) -> T1A bf16 A-form [64 e][128 k] (over dead A_in)
    {
        const int kcol = w*16 + (l & 15);
        const float bk = bs1[kcol];
        #pragma unroll
        for (int et = 0; et < 4; ++et)
            #pragma unroll
            for (int r = 0; r < 4; ++r)
                *(unsigned short*)((char*)sm + T1A_B + (et*16 + (kg<<2) + r)*272 + kcol*2)
                    = f2bf(fmaxf(accv[et][r] + bk, 0.0f));
    }
    __syncthreads();

    // P5: ef = t1 @ Ws2 + bs2 (MFMA, K=128) -> global efb (bf16, guarded) + EFA bf16
    {
        short8 a5[4];
        #pragma unroll
        for (int s = 0; s < 4; ++s)
            a5[s] = *(const short8*)((const char*)sm + T1A_B + arow*272 + s*64 + akoff);
        const short8* Bf = (const short8*)(fb + FB_WS2);
        #pragma unroll
        for (int tt = 0; tt < 2; ++tt) {
            const int tn = cA + tt*2;
            f32x4 acc = {0.f, 0.f, 0.f, 0.f};
            #pragma unroll
            for (int s = 0; s < 4; ++s)
                acc = __builtin_amdgcn_mfma_f32_16x16x32_bf16(a5[s], Bf[(s*4 + tn)*64 + l], acc, 0, 0, 0);
            const int col = tn*16 + (l & 15);
            const float bb = bs2[col];
            #pragma unroll
            for (int r = 0; r < 4; ++r) {
                const unsigned short bv = f2bf(acc[r] + bb);
                if (e0 + orow + r < EE)
                    efb_out[(size_t)(e0 + orow + r)*64 + col] = bv;
                *(unsigned short*)((char*)sm + EFA_B + (orow + r)*144 + col*2) = bv;
            }
        }
    }
    __syncthreads();

    // P6: v = silu(ef @ Wc1 + bc1) (MFMA, K=64) -> V f32 (over dead GF32)
    {
        short8 a6[2];
        #pragma unroll
        for (int s = 0; s < 2; ++s)
            a6[s] = *(const short8*)((const char*)sm + EFA_B + arow*144 + s*64 + akoff);
        const short8* Bf = (const short8*)(fb + FB_WC1);
        #pragma unroll
        for (int tt = 0; tt < 2; ++tt) {
            const int tn = cA + tt*2;
            f32x4 acc = {0.f, 0.f, 0.f, 0.f};
            #pragma unroll
            for (int s = 0; s < 2; ++s)
                acc = __builtin_amdgcn_mfma_f32_16x16x32_bf16(a6[s], Bf[(s*4 + tn)*64 + l], acc, 0, 0, 0);
            const int col = tn*16 + (l & 15);
            const float bb = bc1[col];
            #pragma unroll
            for (int r = 0; r < 4; ++r)
                sm[GF32_F + col*72 + orow + r] = siluf(acc[r] + bb);
        }
    }
    __syncthreads();

    // P7: cw = v . Wc2 -> trans (guarded)
    if (t < 64 && e0 + t < EE) {
        float cw = 0.0f;
        for (int f = 0; f < 64; ++f) cw = fmaf(sm[GF32_F + f*72 + t], Wc2[f], cw);
        const int eid = e0 + t;
        trans_out[eid*3 + 0] = s_cd[t]     * cw;
        trans_out[eid*3 + 1] = s_cd[64+t]  * cw;
        trans_out[eid*3 + 2] = s_cd[128+t] * cw;
    }
}

__global__ __launch_bounds__(512, 2)
void egcl_node_kernel(const float* __restrict__ h, const float* __restrict__ coord,
                      const int* __restrict__ ei,
                      const unsigned short* __restrict__ fb,
                      const float* __restrict__ bn1, const float* __restrict__ bn2,
                      const unsigned short* __restrict__ efb, const float* __restrict__ trans,
                      const int* __restrict__ off, const int* __restrict__ eidx,
                      float* __restrict__ out)
{
    __shared__ __attribute__((aligned(16))) float smn[NSM_FLOATS];
    const int t = threadIdx.x;
    const int n0 = blockIdx.x * 32;
    const int l = t & 63, w = t >> 6;
    const int mt = w & 1, tn4 = w >> 1;
    const int kg = l >> 4;
    const int arow = mt * 16 + (l & 15);
    const int akoff = kg * 16;
    const int orow = mt * 16 + (kg << 2);
    const int col = tn4 * 16 + (l & 15);

    // stage Wn1 + Wn2 frags
    for (int i = t*8; i < 10240; i += 4096)
        *(f32x4*)&smn[NW1_F + (i >> 1)] = *(const f32x4*)&fb[FB_WN1 + i];
    for (int i = t*8; i < 5120; i += 4096)
        *(f32x4*)&smn[NW2_F + (i >> 1)] = *(const f32x4*)&fb[FB_WN2 + i];

    // N1 gather: m = [h(64), rel(3), agg(64), 0-pad] bf16 A-form + h_pos f32
    {
        const int nd = t >> 4, fg = t & 15;
        const int gn = n0 + nd;
        const f32x4 hv = *(const f32x4*)&h[(size_t)gn*64 + fg*4];
        #pragma unroll
        for (int u = 0; u < 4; ++u) {
            smn[NHP_F + nd*68 + fg*4 + u] = hv[u];
            *(unsigned short*)((char*)smn + NMA_B + nd*336 + (fg*4+u)*2) = f2bf(hv[u]);
        }
        const int o0 = off[gn], o1 = off[gn + 1];
        float acc[4] = {0.f, 0.f, 0.f, 0.f};
        for (int j = o0; j < o1; ++j) {
            const int e2 = eidx[j];
            const unsigned short* ep = &efb[(size_t)e2*64 + fg*4];
            #pragma unroll
            for (int u = 0; u < 4; ++u) acc[u] += bf2f(ep[u]);
        }
        #pragma unroll
        for (int u = 0; u < 4; ++u)
            *(unsigned short*)((char*)smn + NMA_B + nd*336 + (67+fg*4+u)*2) = f2bf(acc[u]);
    }
    if (t < 32) {
        const int gn = n0 + t;
        const int r = ei[gn], c = ei[EE + gn];   // rel for node n comes from edge n (E==N)
        const float dx = coord[r*3+0] - coord[c*3+0];
        const float dy = coord[r*3+1] - coord[c*3+1];
        const float dz = coord[r*3+2] - coord[c*3+2];
        const float inv = 1.0f / (sqrtf(dx*dx + dy*dy + dz*dz) + 1e-8f);
        const float rl[3] = {dx*inv, dy*inv, dz*inv};
        #pragma unroll
        for (int k = 0; k < 3; ++k) {
            smn[NHP_F + t*68 + 64 + k] = rl[k];
            *(unsigned short*)((char*)smn + NMA_B + t*336 + (64+k)*2) = f2bf(rl[k]);
        }
        #pragma unroll
        for (int cz = 131; cz < 136; ++cz)
            *(unsigned short*)((char*)smn + NMA_B + t*336 + cz*2) = 0;
        const short8 z8 = {0,0,0,0,0,0,0,0};
        #pragma unroll
        for (int ch = 17; ch < 20; ++ch)
            *(short8*)((char*)smn + NMA_B + t*336 + ch*16) = z8;
        const int o0 = off[gn], o1 = off[gn + 1];
        float nx = 0.f, ny = 0.f, nz = 0.f;
        for (int j = o0; j < o1; ++j) {
            const int e2 = eidx[j];
            nx += trans[e2*3 + 0];
            ny += trans[e2*3 + 1];
            nz += trans[e2*3 + 2];
        }
        const float cnt = fmaxf((float)(o1 - o0), 1.0f);
        out[NN*67 + gn*3 + 0] = coord[gn*3 + 0] + nx / cnt;
        out[NN*67 + gn*3 + 1] = coord[gn*3 + 1] + ny / cnt;
        out[NN*67 + gn*3 + 2] = coord[gn*3 + 2] + nz / cnt;
    }
    __syncthreads();

    // N2: z = silu(m @ Wn1 + bn1) (MFMA, K=160) -> NZA bf16
    {
        f32x4 acc = {0.f, 0.f, 0.f, 0.f};
        #pragma unroll
        for (int s = 0; s < 5; ++s) {
            const short8 a = *(const short8*)((const char*)smn + NMA_B + arow*336 + s*64 + akoff);
            const short8 b = *(const short8*)((const char*)smn + NW1_B + ((s*4 + tn4)*64 + l)*16);
            acc = __builtin_amdgcn_mfma_f32_16x16x32_bf16(a, b, acc, 0, 0, 0);
        }
        const float bb = bn1[col];
        #pragma unroll
        for (int r = 0; r < 4; ++r)
            *(unsigned short*)((char*)smn + NZA_B + (orow + r)*144 + col*2)
                = f2bf(siluf(acc[r] + bb));
    }
    __syncthreads();

    // N3: h_out = h_pos + z @ Wn2 + bn2  (10 tiles of 16 cols over 8 waves)
    for (int tid = w; tid < 10; tid += 8) {
        const int mtN = tid & 1, tnN = tid >> 1;
        f32x4 acc = {0.f, 0.f, 0.f, 0.f};
        #pragma unroll
        for (int s = 0; s < 2; ++s) {
            const short8 a = *(const short8*)((const char*)smn + NZA_B + (mtN*16 + (l & 15))*144 + s*64 + akoff);
            const short8 b = *(const short8*)((const char*)smn + NW2_B + ((s*5 + tnN)*64 + l)*16);
            acc = __builtin_amdgcn_mfma_f32_16x16x32_bf16(a, b, acc, 0, 0, 0);
        }
        const int colN = tnN*16 + (l & 15);
        if (colN < 67) {
            const float bb = bn2[colN];
            #pragma unroll
            for (int r = 0; r < 4; ++r) {
                const int row = mtN*16 + (kg << 2) + r;
                out[(size_t)(n0 + row)*67 + colN] = smn[NHP_F + row*68 + colN] + acc[r] + bb;
            }
        }
    }
}

extern "C" void kernel_launch(void* const* d_in, const int* in_sizes, int n_in,
                              void* d_out, int out_size, void* d_ws, size_t ws_size,
                              hipStream_t stream)
{
    (void)in_sizes; (void)n_in; (void)out_size; (void)ws_size;
    const float* h     = (const float*)d_in[0];
    const float* coord = (const float*)d_in[1];
    const int*   ei    = (const int*)d_in[2];
    const float* We1   = (const float*)d_in[3];
    const float* be1   = (const float*)d_in[4];
    const float* We2   = (const float*)d_in[5];
    const float* be2   = (const float*)d_in[6];
    const float* Ws1   = (const float*)d_in[7];
    const float* bs1   = (const float*)d_in[8];
    const float* Ws2   = (const float*)d_in[9];
    const float* bs2   = (const float*)d_in[10];
    const float* Wc1   = (const float*)d_in[11];
    const float* bc1   = (const float*)d_in[12];
    const float* Wc2   = (const float*)d_in[13];
    const float* Wn1   = (const float*)d_in[14];
    const float* bn1   = (const float*)d_in[15];
    const float* Wn2   = (const float*)d_in[16];
    const float* bn2   = (const float*)d_in[17];
    float* ws  = (float*)d_ws;
    float* out = (float*)d_out;

    unsigned short* efb = (unsigned short*)(ws + WS_EFB);
    float* trans = ws + WS_TRANS;
    int* cnti = (int*)(ws + WS_CNTI);
    int* off  = (int*)(ws + WS_OFF);
    int* cur  = (int*)(ws + WS_CUR);
    int* eidx = (int*)(ws + WS_EIDX);
    unsigned short* ws1s = (unsigned short*)(ws + WS_AL);
    unsigned short* fbb  = ws1s + WS1S_ELEMS;

    hipMemsetAsync((void*)cnti, 0, (size_t)NN * sizeof(int), stream);
    prep_all<<<277 + (EE + 255)/256, 256, 0, stream>>>(Ws1, We1, We2, Ws2, Wc1, Wn1, Wn2,
                                                       ws1s, fbb, ei, cnti);
    scan_csr<<<1, 1024, 0, stream>>>(cnti, off, cur);
    egcl_edge_kernel<<<(EE + 63)/64, 512, 0, stream>>>(h, coord, ei, fbb, be1, be2,
                                                       ws1s, bs1, bs2, bc1, Wc2,
                                                       cur, eidx, efb, trans);
    egcl_node_kernel<<<NN/32, 512, 0, stream>>>(h, coord, ei, fbb, bn1, bn2,
                                                efb, trans, off, eidx, out);
}

// Round 16
// 91.804 us; speedup vs baseline: 2.8064x; 1.0562x over previous
//
#include <hip/hip_runtime.h>

#define NN 20000
#define EE 20000

typedef __attribute__((ext_vector_type(8))) short short8;
typedef __attribute__((ext_vector_type(4))) float f32x4;

// workspace layout (float indices)
#define WS_EFB    0                         // edge_feat bf16 [E][64] = 640000 f32 units
#define WS_TRANS  640000                    // trans f32 [E][3]
#define WS_CNTI   700000                    // int cnt[N]
#define WS_OFF    720000                    // int off[N+1]
#define WS_CUR    740001                    // int cursor[N]
#define WS_EIDX   760001                    // int eidx[E]
#define WS_CORE_END 780001
#define WS_AL     ((WS_CORE_END + 3) & ~3)
#define WS1S_ELEMS (4096*128)               // bf16: swizzled 64*Ws1 (1 MB)
// MLP weight fragment buffers (bf16 elems)
#define FB_WE1 0        // K=129->160, 5 steps : 10240
#define FB_WE2 10240    // K=64, 2 steps       : 4096
#define FB_WS2 14336    // K=128, 4 steps      : 8192
#define FB_WC1 22528    // K=64, 2 steps       : 4096
#define FB_WN1 26624    // K=131->160, 5 steps : 10240
#define FB_WN2 36864    // K=64, 2 steps, 5 tn : 5120
#define FB_ELEMS 41984

// edge-kernel LDS (f32 indices) — 64-edge blocks, no weight staging (frags from L2)
#define AIN_F   0        // A_in bf16 [64][336B] = 5376 f32 ; later T1A bf16 [64][272B]
#define E1A_F   5376     // e1 / ef bf16 A-form [64][144B] = 2304 f32
#define GF32_F  7680     // g f32 [64 i][72] (stride 72) ; later v   = 4608 f32
#define GA_F    12288    // g bf16 A-form [64][144B] = 2304 f32
#define SM_FLOATS 14592  // 58.4 KB
#define AIN_B   0
#define T1A_B   0
#define E1A_B   (E1A_F*4)
#define EFA_B   (E1A_F*4)
#define GA_B    (GA_F*4)

// node-kernel LDS (f32 indices) — weights read direct from L2 (no staging)
#define NMA_B   0        // m bf16 [32][336B] = 2688 f32
#define NHP_F   2688     // h_pos f32 [32][68] = 2176
#define NZA_F   4864     // z bf16 A-form [32][144B] = 1152 f32
#define NSM_FLOATS 6016  // 24.1 KB
#define NZA_B   (NZA_F*4)

__device__ __forceinline__ float siluf(float x) {
    return x * (1.0f / (1.0f + __expf(-x)));
}
__device__ __forceinline__ unsigned short f2bf(float f) {
    union { float f; unsigned u; } v; v.f = f;
    return (unsigned short)((v.u + 0x7FFF + ((v.u >> 16) & 1)) >> 16);
}
__device__ __forceinline__ float bf2f(unsigned short x) {
    union { unsigned u; float f; } v; v.u = ((unsigned)x) << 16; return v.f;
}

// ---------- CSR scan (fill is fused into the edge kernel) ----------
__global__ void scan_csr(const int* __restrict__ cnt, int* __restrict__ off,
                         int* __restrict__ cursor) {
    const int t = threadIdx.x;        // 1024 threads, 20 items each
    __shared__ int ps[1024];
    int loc[20];
    int s = 0;
    const int base = t * 20;
    #pragma unroll
    for (int k = 0; k < 20; ++k) {
        const int i = base + k;
        const int c = (i < NN) ? cnt[i] : 0;
        loc[k] = s; s += c;
    }
    ps[t] = s;
    __syncthreads();
    for (int d = 1; d < 1024; d <<= 1) {
        const int v = (t >= d) ? ps[t - d] : 0;
        __syncthreads();
        ps[t] += v;
        __syncthreads();
    }
    const int excl = ps[t] - s;
    #pragma unroll
    for (int k = 0; k < 20; ++k) {
        const int i = base + k;
        if (i < NN) { const int v = excl + loc[k]; off[i] = v; cursor[i] = v; }
    }
    if (t == 1023) off[NN] = ps[1023];
}

// ---------- combined prep: SO3 B swizzle + all MLP frag buffers + degree histogram ----------
__global__ void prep_all(const float* __restrict__ Ws1,
                         const float* __restrict__ We1, const float* __restrict__ We2,
                         const float* __restrict__ Ws2, const float* __restrict__ Wc1,
                         const float* __restrict__ Wn1, const float* __restrict__ Wn2,
                         unsigned short* __restrict__ ws1s, unsigned short* __restrict__ fbb,
                         const int* __restrict__ ei, int* __restrict__ cnt)
{
    const int b = blockIdx.x, t = threadIdx.x;
    if (b < 256) {
        // ws1s[((s*8+tn)*64 + l)*8 + u] = bf16(64*Ws1[(s*32 + 8*(l>>4) + u)][tn*16 + (l&15)])
        const int tid = b * 256 + t;
        const int l = tid & 63, fid = tid >> 6;
        const int s = fid >> 3, tn = fid & 7;
        const int krow = s * 32 + 8 * (l >> 4);
        const int ncol = tn * 16 + (l & 15);
        short8 frag;
        #pragma unroll
        for (int u = 0; u < 8; ++u)
            frag[u] = (short)f2bf(64.0f * Ws1[(krow + u) * 128 + ncol]);
        *(short8*)&ws1s[(size_t)tid * 8] = frag;
    } else if (b < 277) {
        const int idx = (b - 256) * 256 + t;   // 0..5375, valid < 5248
        if (idx < 5248) {
            const float* W; int K, NC, NTN; unsigned short* dst; int local;
            if (idx < 1280)      { W = We1; K = 129; NC = 64; NTN = 4; dst = fbb + FB_WE1; local = idx; }
            else if (idx < 1792) { W = We2; K = 64;  NC = 64; NTN = 4; dst = fbb + FB_WE2; local = idx - 1280; }
            else if (idx < 2816) { W = Ws2; K = 128; NC = 64; NTN = 4; dst = fbb + FB_WS2; local = idx - 1792; }
            else if (idx < 3328) { W = Wc1; K = 64;  NC = 64; NTN = 4; dst = fbb + FB_WC1; local = idx - 2816; }
            else if (idx < 4608) { W = Wn1; K = 131; NC = 64; NTN = 4; dst = fbb + FB_WN1; local = idx - 3328; }
            else                 { W = Wn2; K = 64;  NC = 67; NTN = 5; dst = fbb + FB_WN2; local = idx - 4608; }
            const int per = NTN * 64;
            const int s = local / per, rem = local % per, tn = rem >> 6, ll = rem & 63;
            const int ccol = tn * 16 + (ll & 15), kr0 = s * 32 + 8 * (ll >> 4);
            short8 frag;
            #pragma unroll
            for (int u = 0; u < 8; ++u) {
                const int kr = kr0 + u;
                frag[u] = (kr < K && ccol < NC) ? (short)f2bf(W[kr * NC + ccol]) : (short)0;
            }
            *(short8*)&dst[local * 8] = frag;
        }
    } else {
        const int e = (b - 277) * 256 + t;
        if (e < EE) atomicAdd(&cnt[ei[e]], 1);
    }
}

// 64 edges/block, 512 threads. __launch_bounds__(512, 2) is the ONLY pair the
// allocator has honored with a ~110-reg budget (R8/R13: VGPR 104-116, no spill);
// (512,4) and (1024,4) both flipped to the 64-reg bucket and spilled ~500 MB.
__global__ __launch_bounds__(512, 2)
void egcl_edge_kernel(const float* __restrict__ h, const float* __restrict__ coord,
                      const int* __restrict__ ei,
                      const unsigned short* __restrict__ fb,
                      const float* __restrict__ be1, const float* __restrict__ be2,
                      const unsigned short* __restrict__ Ws1s, const float* __restrict__ bs1,
                      const float* __restrict__ bs2, const float* __restrict__ bc1,
                      const float* __restrict__ Wc2,
                      int* __restrict__ cur, int* __restrict__ eidx,
                      unsigned short* __restrict__ efb_out, float* __restrict__ trans_out)
{
    __shared__ __attribute__((aligned(16))) float sm[SM_FLOATS];
    __shared__ int s_row[64], s_col[64];
    __shared__ float s_cd[192], s_rad[64];

    const int t = threadIdx.x;
    const int e0 = blockIdx.x * 64;    // 313 blocks; last block: 48 valid edges
    const int l = t & 63, w = t >> 6;
    const int kg = l >> 4;
    const int akoff = kg * 16;
    // MLP tiling: wave w owns row-tile (w&3), col-tiles (w>>2) and (w>>2)+2
    const int mrow = (w & 3) * 16;
    const int arow = mrow + (l & 15);
    const int orow = mrow + (kg << 2);
    const int cA = w >> 2;

    if (t < 64) {
        const int eid = min(e0 + t, EE - 1);
        const int r = ei[eid], c = ei[EE + eid];
        s_row[t] = r; s_col[t] = c;
        const float dx = coord[r*3+0] - coord[c*3+0];
        const float dy = coord[r*3+1] - coord[c*3+1];
        const float dz = coord[r*3+2] - coord[c*3+2];
        s_cd[t] = dx; s_cd[64+t] = dy; s_cd[128+t] = dz;
        s_rad[t] = dx*dx + dy*dy + dz*dz;
        // fused CSR fill (scan_csr ran before this kernel; node runs after)
        if (e0 + t < EE) {
            const int p = atomicAdd(&cur[r], 1);
            eidx[p] = e0 + t;
        }
    }
    __syncthreads();

    // P1: gather A_in bf16 [64 e][160k pad->336B] = [h_row(64), h_col(64), radial, 0]
    {
        const int ee = t >> 3, fg8 = t & 7;
        const int r = s_row[ee], c = s_col[ee];
        short8 fr, fc;
        #pragma unroll
        for (int u = 0; u < 8; ++u) fr[u] = (short)f2bf(h[(size_t)r*64 + fg8*8 + u]);
        #pragma unroll
        for (int u = 0; u < 8; ++u) fc[u] = (short)f2bf(h[(size_t)c*64 + fg8*8 + u]);
        *(short8*)((char*)sm + AIN_B + ee*336 + fg8*16)       = fr;
        *(short8*)((char*)sm + AIN_B + ee*336 + (8+fg8)*16)   = fc;
        if (fg8 < 5) {
            short8 z = {0,0,0,0,0,0,0,0};
            if (fg8 == 0) z[0] = (short)f2bf(s_rad[ee]);
            *(short8*)((char*)sm + AIN_B + ee*336 + (16 + fg8)*16) = z;
        }
    }
    __syncthreads();

    // P2: e1 = silu(in @ We1 + be1) (MFMA, K=160; B-frags direct from L2) -> E1A bf16
    {
        short8 a2[5];
        #pragma unroll
        for (int s = 0; s < 5; ++s)
            a2[s] = *(const short8*)((const char*)sm + AIN_B + arow*336 + s*64 + akoff);
        const short8* Bf = (const short8*)(fb + FB_WE1);
        #pragma unroll
        for (int tt = 0; tt < 2; ++tt) {
            const int tn = cA + tt*2;
            f32x4 acc = {0.f, 0.f, 0.f, 0.f};
            #pragma unroll
            for (int s = 0; s < 5; ++s)
                acc = __builtin_amdgcn_mfma_f32_16x16x32_bf16(a2[s], Bf[(s*4 + tn)*64 + l], acc, 0, 0, 0);
            const int col = tn*16 + (l & 15);
            const float bb = be1[col];
            #pragma unroll
            for (int r = 0; r < 4; ++r)
                *(unsigned short*)((char*)sm + E1A_B + (orow + r)*144 + col*2)
                    = f2bf(siluf(acc[r] + bb));
        }
    }
    __syncthreads();

    // P3: g = silu(e1 @ We2 + be2) (MFMA, K=64) -> GF32 f32 [i][72] + GA bf16 A-form
    {
        short8 a3[2];
        #pragma unroll
        for (int s = 0; s < 2; ++s)
            a3[s] = *(const short8*)((const char*)sm + E1A_B + arow*144 + s*64 + akoff);
        const short8* Bf = (const short8*)(fb + FB_WE2);
        #pragma unroll
        for (int tt = 0; tt < 2; ++tt) {
            const int tn = cA + tt*2;
            f32x4 acc = {0.f, 0.f, 0.f, 0.f};
            #pragma unroll
            for (int s = 0; s < 2; ++s)
                acc = __builtin_amdgcn_mfma_f32_16x16x32_bf16(a3[s], Bf[(s*4 + tn)*64 + l], acc, 0, 0, 0);
            const int col = tn*16 + (l & 15);
            const float bb = be2[col];
            #pragma unroll
            for (int r = 0; r < 4; ++r) {
                const float sv = siluf(acc[r] + bb);
                sm[GF32_F + col*72 + orow + r] = sv;
                *(unsigned short*)((char*)sm + GA_B + (orow + r)*144 + col*2) = f2bf(sv);
            }
        }
    }
    __syncthreads();

    // P4: SO3 GEMM acc[e,k] = sum_i g[e,i]*(g_bf16[e,:] @ 64*Ws1_i[:,k])
    // Wave w owns cols [w*16,+16) x 64 edges. B: L2 -> registers, 2 banks x 4 steps,
    // compiler-counted vmcnt, zero barriers. PER-BLOCK PHASE ROTATION (grot): all
    // blocks otherwise walk the identical Bp address sequence in lockstep -> every
    // CU hits the same L2 line/channel simultaneously (measured: per-wave rate rose
    // 1.5x when block count halved). Rotating the i-group start spreads concurrent
    // reads across 32 regions. Accumulation over i is order-independent.
    const int grot = blockIdx.x & 31;

    short8 A[4][2];
    #pragma unroll
    for (int et = 0; et < 4; ++et)
        #pragma unroll
        for (int kh = 0; kh < 2; ++kh)
            A[et][kh] = *(const short8*)((const char*)sm + GA_B +
                                         (et*16 + (l & 15))*144 + kh*64 + kg*16);

    float accv[4][4];
    #pragma unroll
    for (int et = 0; et < 4; ++et)
        #pragma unroll
        for (int r = 0; r < 4; ++r) accv[et][r] = 0.0f;

    {
        const short8* Bp = (const short8*)Ws1s;   // frag for step s: Bp[(s*8 + w)*64 + l]
        short8 q0[4], q1[4];

#define LOADBANK(P, G) { \
    const int GG_ = ((G) + grot) & 31; \
    _Pragma("unroll") \
    for (int j = 0; j < 4; ++j) P[j] = Bp[(((GG_*4 + j)*8 + w)*64 + l)]; \
    __builtin_amdgcn_sched_barrier(0); }
#define USEBANK(P, G) { \
    const int GU_ = ((G) + grot) & 31; \
    _Pragma("unroll") \
    for (int ii = 0; ii < 2; ++ii) { \
        const int i_ = 2*GU_ + ii; \
        _Pragma("unroll") \
        for (int et = 0; et < 4; ++et) { \
            f32x4 c = __builtin_amdgcn_mfma_f32_16x16x32_bf16(A[et][0], P[2*ii], (f32x4){0.f,0.f,0.f,0.f}, 0, 0, 0); \
            c = __builtin_amdgcn_mfma_f32_16x16x32_bf16(A[et][1], P[2*ii+1], c, 0, 0, 0); \
            const f32x4 g4 = *(const f32x4*)&sm[GF32_F + i_*72 + et*16 + (kg << 2)]; \
            _Pragma("unroll") \
            for (int r = 0; r < 4; ++r) accv[et][r] = fmaf(g4[r], c[r], accv[et][r]); \
        } \
    } }

        LOADBANK(q0, 0)
        LOADBANK(q1, 1)
        #pragma unroll 1
        for (int m = 0; m < 15; ++m) {
            USEBANK(q0, 2*m)     LOADBANK(q0, 2*m + 2)
            USEBANK(q1, 2*m + 1) LOADBANK(q1, 2*m + 3)
        }
        USEBANK(q0, 30)
        USEBANK(q1, 31)
#undef LOADBANK
#undef USEBANK
    }

    // t1 = relu(acc + bs1) -> T1A bf16 A-form [64 e][128 k] (over dead A_in)
    {
        const int kcol = w*16 + (l & 15);
        const float bk = bs1[kcol];
        #pragma unroll
        for (int et = 0; et < 4; ++et)
            #pragma unroll
            for (int r = 0; r < 4; ++r)
                *(unsigned short*)((char*)sm + T1A_B + (et*16 + (kg<<2) + r)*272 + kcol*2)
                    = f2bf(fmaxf(accv[et][r] + bk, 0.0f));
    }
    __syncthreads();

    // P5: ef = t1 @ Ws2 + bs2 (MFMA, K=128) -> global efb (bf16, guarded) + EFA bf16
    {
        short8 a5[4];
        #pragma unroll
        for (int s = 0; s < 4; ++s)
            a5[s] = *(const short8*)((const char*)sm + T1A_B + arow*272 + s*64 + akoff);
        const short8* Bf = (const short8*)(fb + FB_WS2);
        #pragma unroll
        for (int tt = 0; tt < 2; ++tt) {
            const int tn = cA + tt*2;
            f32x4 acc = {0.f, 0.f, 0.f, 0.f};
            #pragma unroll
            for (int s = 0; s < 4; ++s)
                acc = __builtin_amdgcn_mfma_f32_16x16x32_bf16(a5[s], Bf[(s*4 + tn)*64 + l], acc, 0, 0, 0);
            const int col = tn*16 + (l & 15);
            const float bb = bs2[col];
            #pragma unroll
            for (int r = 0; r < 4; ++r) {
                const unsigned short bv = f2bf(acc[r] + bb);
                if (e0 + orow + r < EE)
                    efb_out[(size_t)(e0 + orow + r)*64 + col] = bv;
                *(unsigned short*)((char*)sm + EFA_B + (orow + r)*144 + col*2) = bv;
            }
        }
    }
    __syncthreads();

    // P6: v = silu(ef @ Wc1 + bc1) (MFMA, K=64) -> V f32 (over dead GF32)
    {
        short8 a6[2];
        #pragma unroll
        for (int s = 0; s < 2; ++s)
            a6[s] = *(const short8*)((const char*)sm + EFA_B + arow*144 + s*64 + akoff);
        const short8* Bf = (const short8*)(fb + FB_WC1);
        #pragma unroll
        for (int tt = 0; tt < 2; ++tt) {
            const int tn = cA + tt*2;
            f32x4 acc = {0.f, 0.f, 0.f, 0.f};
            #pragma unroll
            for (int s = 0; s < 2; ++s)
                acc = __builtin_amdgcn_mfma_f32_16x16x32_bf16(a6[s], Bf[(s*4 + tn)*64 + l], acc, 0, 0, 0);
            const int col = tn*16 + (l & 15);
            const float bb = bc1[col];
            #pragma unroll
            for (int r = 0; r < 4; ++r)
                sm[GF32_F + col*72 + orow + r] = siluf(acc[r] + bb);
        }
    }
    __syncthreads();

    // P7: cw = v . Wc2 -> trans (guarded)
    if (t < 64 && e0 + t < EE) {
        float cw = 0.0f;
        for (int f = 0; f < 64; ++f) cw = fmaf(sm[GF32_F + f*72 + t], Wc2[f], cw);
        const int eid = e0 + t;
        trans_out[eid*3 + 0] = s_cd[t]     * cw;
        trans_out[eid*3 + 1] = s_cd[64+t]  * cw;
        trans_out[eid*3 + 2] = s_cd[128+t] * cw;
    }
}

__global__ __launch_bounds__(512, 2)
void egcl_node_kernel(const float* __restrict__ h, const float* __restrict__ coord,
                      const int* __restrict__ ei,
                      const unsigned short* __restrict__ fb,
                      const float* __restrict__ bn1, const float* __restrict__ bn2,
                      const unsigned short* __restrict__ efb, const float* __restrict__ trans,
                      const int* __restrict__ off, const int* __restrict__ eidx,
                      float* __restrict__ out)
{
    __shared__ __attribute__((aligned(16))) float smn[NSM_FLOATS];
    const int t = threadIdx.x;
    const int n0 = blockIdx.x * 32;
    const int l = t & 63, w = t >> 6;
    const int mt = w & 1, tn4 = w >> 1;
    const int kg = l >> 4;
    const int arow = mt * 16 + (l & 15);
    const int akoff = kg * 16;
    const int orow = mt * 16 + (kg << 2);
    const int col = tn4 * 16 + (l & 15);

    // N1 gather: m = [h(64), rel(3), agg(64), 0-pad] bf16 A-form + h_pos f32
    {
        const int nd = t >> 4, fg = t & 15;
        const int gn = n0 + nd;
        const f32x4 hv = *(const f32x4*)&h[(size_t)gn*64 + fg*4];
        #pragma unroll
        for (int u = 0; u < 4; ++u) {
            smn[NHP_F + nd*68 + fg*4 + u] = hv[u];
            *(unsigned short*)((char*)smn + NMA_B + nd*336 + (fg*4+u)*2) = f2bf(hv[u]);
        }
        const int o0 = off[gn], o1 = off[gn + 1];
        float acc[4] = {0.f, 0.f, 0.f, 0.f};
        for (int j = o0; j < o1; ++j) {
            const int e2 = eidx[j];
            const unsigned short* ep = &efb[(size_t)e2*64 + fg*4];
            #pragma unroll
            for (int u = 0; u < 4; ++u) acc[u] += bf2f(ep[u]);
        }
        #pragma unroll
        for (int u = 0; u < 4; ++u)
            *(unsigned short*)((char*)smn + NMA_B + nd*336 + (67+fg*4+u)*2) = f2bf(acc[u]);
    }
    if (t < 32) {
        const int gn = n0 + t;
        const int r = ei[gn], c = ei[EE + gn];   // rel for node n comes from edge n (E==N)
        const float dx = coord[r*3+0] - coord[c*3+0];
        const float dy = coord[r*3+1] - coord[c*3+1];
        const float dz = coord[r*3+2] - coord[c*3+2];
        const float inv = 1.0f / (sqrtf(dx*dx + dy*dy + dz*dz) + 1e-8f);
        const float rl[3] = {dx*inv, dy*inv, dz*inv};
        #pragma unroll
        for (int k = 0; k < 3; ++k) {
            smn[NHP_F + t*68 + 64 + k] = rl[k];
            *(unsigned short*)((char*)smn + NMA_B + t*336 + (64+k)*2) = f2bf(rl[k]);
        }
        #pragma unroll
        for (int cz = 131; cz < 136; ++cz)
            *(unsigned short*)((char*)smn + NMA_B + t*336 + cz*2) = 0;
        const short8 z8 = {0,0,0,0,0,0,0,0};
        #pragma unroll
        for (int ch = 17; ch < 20; ++ch)
            *(short8*)((char*)smn + NMA_B + t*336 + ch*16) = z8;
        const int o0 = off[gn], o1 = off[gn + 1];
        float nx = 0.f, ny = 0.f, nz = 0.f;
        for (int j = o0; j < o1; ++j) {
            const int e2 = eidx[j];
            nx += trans[e2*3 + 0];
            ny += trans[e2*3 + 1];
            nz += trans[e2*3 + 2];
        }
        const float cnt = fmaxf((float)(o1 - o0), 1.0f);
        out[NN*67 + gn*3 + 0] = coord[gn*3 + 0] + nx / cnt;
        out[NN*67 + gn*3 + 1] = coord[gn*3 + 1] + ny / cnt;
        out[NN*67 + gn*3 + 2] = coord[gn*3 + 2] + nz / cnt;
    }
    __syncthreads();

    // N2: z = silu(m @ Wn1 + bn1) (MFMA, K=160; B direct from L2) -> NZA bf16
    {
        const short8* Bf = (const short8*)(fb + FB_WN1);
        f32x4 acc = {0.f, 0.f, 0.f, 0.f};
        #pragma unroll
        for (int s = 0; s < 5; ++s) {
            const short8 a = *(const short8*)((const char*)smn + NMA_B + arow*336 + s*64 + akoff);
            acc = __builtin_amdgcn_mfma_f32_16x16x32_bf16(a, Bf[(s*4 + tn4)*64 + l], acc, 0, 0, 0);
        }
        const float bb = bn1[col];
        #pragma unroll
        for (int r = 0; r < 4; ++r)
            *(unsigned short*)((char*)smn + NZA_B + (orow + r)*144 + col*2)
                = f2bf(siluf(acc[r] + bb));
    }
    __syncthreads();

    // N3: h_out = h_pos + z @ Wn2 + bn2  (10 tiles of 16 cols over 8 waves; B from L2)
    for (int tid = w; tid < 10; tid += 8) {
        const int mtN = tid & 1, tnN = tid >> 1;
        const short8* Bf = (const short8*)(fb + FB_WN2);
        f32x4 acc = {0.f, 0.f, 0.f, 0.f};
        #pragma unroll
        for (int s = 0; s < 2; ++s) {
            const short8 a = *(const short8*)((const char*)smn + NZA_B + (mtN*16 + (l & 15))*144 + s*64 + akoff);
            acc = __builtin_amdgcn_mfma_f32_16x16x32_bf16(a, Bf[(s*5 + tnN)*64 + l], acc, 0, 0, 0);
        }
        const int colN = tnN*16 + (l & 15);
        if (colN < 67) {
            const float bb = bn2[colN];
            #pragma unroll
            for (int r = 0; r < 4; ++r) {
                const int row = mtN*16 + (kg << 2) + r;
                out[(size_t)(n0 + row)*67 + colN] = smn[NHP_F + row*68 + colN] + acc[r] + bb;
            }
        }
    }
}

extern "C" void kernel_launch(void* const* d_in, const int* in_sizes, int n_in,
                              void* d_out, int out_size, void* d_ws, size_t ws_size,
                              hipStream_t stream)
{
    (void)in_sizes; (void)n_in; (void)out_size; (void)ws_size;
    const float* h     = (const float*)d_in[0];
    const float* coord = (const float*)d_in[1];
    const int*   ei    = (const int*)d_in[2];
    const float* We1   = (const float*)d_in[3];
    const float* be1   = (const float*)d_in[4];
    const float* We2   = (const float*)d_in[5];
    const float* be2   = (const float*)d_in[6];
    const float* Ws1   = (const float*)d_in[7];
    const float* bs1   = (const float*)d_in[8];
    const float* Ws2   = (const float*)d_in[9];
    const float* bs2   = (const float*)d_in[10];
    const float* Wc1   = (const float*)d_in[11];
    const float* bc1   = (const float*)d_in[12];
    const float* Wc2   = (const float*)d_in[13];
    const float* Wn1   = (const float*)d_in[14];
    const float* bn1   = (const float*)d_in[15];
    const float* Wn2   = (const float*)d_in[16];
    const float* bn2   = (const float*)d_in[17];
    float* ws  = (float*)d_ws;
    float* out = (float*)d_out;

    unsigned short* efb = (unsigned short*)(ws + WS_EFB);
    float* trans = ws + WS_TRANS;
    int* cnti = (int*)(ws + WS_CNTI);
    int* off  = (int*)(ws + WS_OFF);
    int* cur  = (int*)(ws + WS_CUR);
    int* eidx = (int*)(ws + WS_EIDX);
    unsigned short* ws1s = (unsigned short*)(ws + WS_AL);
    unsigned short* fbb  = ws1s + WS1S_ELEMS;

    hipMemsetAsync((void*)cnti, 0, (size_t)NN * sizeof(int), stream);
    prep_all<<<277 + (EE + 255)/256, 256, 0, stream>>>(Ws1, We1, We2, Ws2, Wc1, Wn1, Wn2,
                                                       ws1s, fbb, ei, cnti);
    scan_csr<<<1, 1024, 0, stream>>>(cnti, off, cur);
    egcl_edge_kernel<<<(EE + 63)/64, 512, 0, stream>>>(h, coord, ei, fbb, be1, be2,
                                                       ws1s, bs1, bs2, bc1, Wc2,
                                                       cur, eidx, efb, trans);
    egcl_node_kernel<<<NN/32, 512, 0, stream>>>(h, coord, ei, fbb, bn1, bn2,
                                                efb, trans, off, eidx, out);
}

// Round 17
// 90.824 us; speedup vs baseline: 2.8367x; 1.0108x over previous
//
#include <hip/hip_runtime.h>

#define NN 20000
#define EE 20000

typedef __attribute__((ext_vector_type(8))) short short8;
typedef __attribute__((ext_vector_type(4))) float f32x4;

// workspace layout (float indices)
#define WS_EFB    0                         // edge_feat bf16 [E][64] = 640000 f32 units
#define WS_TRANS  640000                    // trans f32 [E][3]
#define WS_CNTI   700000                    // int cnt[N]
#define WS_OFF    720000                    // int off[N+1]
#define WS_CUR    740001                    // int cursor[N]
#define WS_EIDX   760001                    // int eidx[E]
#define WS_CORE_END 780001
#define WS_AL     ((WS_CORE_END + 3) & ~3)
#define WS1S_ELEMS (4096*128)               // bf16: swizzled 64*Ws1 (1 MB)
// MLP weight fragment buffers (bf16 elems)
#define FB_WE1 0        // K=129->160, 5 steps : 10240
#define FB_WE2 10240    // K=64, 2 steps       : 4096
#define FB_WS2 14336    // K=128, 4 steps      : 8192
#define FB_WC1 22528    // K=64, 2 steps       : 4096
#define FB_WN1 26624    // K=131->160, 5 steps : 10240
#define FB_WN2 36864    // K=64, 2 steps, 5 tn : 5120
#define FB_ELEMS 41984

// edge-kernel LDS (f32 indices) — 64-edge blocks, no weight staging (frags from L2)
#define AIN_F   0        // A_in bf16 [64][336B] = 5376 f32 ; later T1A bf16 [64][272B]
#define E1A_F   5376     // e1 / ef bf16 A-form [64][144B] = 2304 f32
#define GF32_F  7680     // g f32 [64 i][72] (stride 72) ; later v   = 4608 f32
#define GA_F    12288    // g bf16 A-form [64][144B] = 2304 f32
#define SM_FLOATS 14592  // 58.4 KB
#define AIN_B   0
#define T1A_B   0
#define E1A_B   (E1A_F*4)
#define EFA_B   (E1A_F*4)
#define GA_B    (GA_F*4)

// node-kernel LDS (f32 indices) — weights read direct from L2 (no staging)
#define NMA_B   0        // m bf16 [32][336B] = 2688 f32
#define NHP_F   2688     // h_pos f32 [32][68] = 2176
#define NZA_F   4864     // z bf16 A-form [32][144B] = 1152 f32
#define NSM_FLOATS 6016  // 24.1 KB
#define NZA_B   (NZA_F*4)

__device__ __forceinline__ float siluf(float x) {
    return x * (1.0f / (1.0f + __expf(-x)));
}
__device__ __forceinline__ unsigned short f2bf(float f) {
    union { float f; unsigned u; } v; v.f = f;
    return (unsigned short)((v.u + 0x7FFF + ((v.u >> 16) & 1)) >> 16);
}
__device__ __forceinline__ float bf2f(unsigned short x) {
    union { unsigned u; float f; } v; v.u = ((unsigned)x) << 16; return v.f;
}

// ---------- CSR scan (fill is fused into the edge kernel) ----------
__global__ void scan_csr(const int* __restrict__ cnt, int* __restrict__ off,
                         int* __restrict__ cursor) {
    const int t = threadIdx.x;        // 1024 threads, 20 items each
    __shared__ int ps[1024];
    int loc[20];
    int s = 0;
    const int base = t * 20;
    #pragma unroll
    for (int k = 0; k < 20; ++k) {
        const int i = base + k;
        const int c = (i < NN) ? cnt[i] : 0;
        loc[k] = s; s += c;
    }
    ps[t] = s;
    __syncthreads();
    for (int d = 1; d < 1024; d <<= 1) {
        const int v = (t >= d) ? ps[t - d] : 0;
        __syncthreads();
        ps[t] += v;
        __syncthreads();
    }
    const int excl = ps[t] - s;
    #pragma unroll
    for (int k = 0; k < 20; ++k) {
        const int i = base + k;
        if (i < NN) { const int v = excl + loc[k]; off[i] = v; cursor[i] = v; }
    }
    if (t == 1023) off[NN] = ps[1023];
}

// ---------- combined prep: SO3 B swizzle + all MLP frag buffers + degree histogram ----------
__global__ void prep_all(const float* __restrict__ Ws1,
                         const float* __restrict__ We1, const float* __restrict__ We2,
                         const float* __restrict__ Ws2, const float* __restrict__ Wc1,
                         const float* __restrict__ Wn1, const float* __restrict__ Wn2,
                         unsigned short* __restrict__ ws1s, unsigned short* __restrict__ fbb,
                         const int* __restrict__ ei, int* __restrict__ cnt)
{
    const int b = blockIdx.x, t = threadIdx.x;
    if (b < 256) {
        // PER-WAVE-CONTIGUOUS layout: frag for (wave tn, step s) at ((tn*128+s)*64+l).
        // Value mapping unchanged: bf16(64*Ws1[(s*32 + 8*(l>>4) + u)][tn*16 + (l&15)])
        const int tid = b * 256 + t;
        const int l = tid & 63, fid = tid >> 6;
        const int s = fid >> 3, tn = fid & 7;
        const int krow = s * 32 + 8 * (l >> 4);
        const int ncol = tn * 16 + (l & 15);
        short8 frag;
        #pragma unroll
        for (int u = 0; u < 8; ++u)
            frag[u] = (short)f2bf(64.0f * Ws1[(krow + u) * 128 + ncol]);
        *(short8*)&ws1s[(size_t)((tn * 128 + s) * 64 + l) * 8] = frag;
    } else if (b < 277) {
        const int idx = (b - 256) * 256 + t;   // 0..5375, valid < 5248
        if (idx < 5248) {
            const float* W; int K, NC, NTN; unsigned short* dst; int local;
            if (idx < 1280)      { W = We1; K = 129; NC = 64; NTN = 4; dst = fbb + FB_WE1; local = idx; }
            else if (idx < 1792) { W = We2; K = 64;  NC = 64; NTN = 4; dst = fbb + FB_WE2; local = idx - 1280; }
            else if (idx < 2816) { W = Ws2; K = 128; NC = 64; NTN = 4; dst = fbb + FB_WS2; local = idx - 1792; }
            else if (idx < 3328) { W = Wc1; K = 64;  NC = 64; NTN = 4; dst = fbb + FB_WC1; local = idx - 2816; }
            else if (idx < 4608) { W = Wn1; K = 131; NC = 64; NTN = 4; dst = fbb + FB_WN1; local = idx - 3328; }
            else                 { W = Wn2; K = 64;  NC = 67; NTN = 5; dst = fbb + FB_WN2; local = idx - 4608; }
            const int per = NTN * 64;
            const int s = local / per, rem = local % per, tn = rem >> 6, ll = rem & 63;
            const int ccol = tn * 16 + (ll & 15), kr0 = s * 32 + 8 * (ll >> 4);
            short8 frag;
            #pragma unroll
            for (int u = 0; u < 8; ++u) {
                const int kr = kr0 + u;
                frag[u] = (kr < K && ccol < NC) ? (short)f2bf(W[kr * NC + ccol]) : (short)0;
            }
            *(short8*)&dst[local * 8] = frag;
        }
    } else {
        const int e = (b - 277) * 256 + t;
        if (e < EE) atomicAdd(&cnt[ei[e]], 1);
    }
}

// 64 edges/block, 512 threads. __launch_bounds__(512, 2) is the ONLY pair the
// allocator has honored with a ~110-reg budget (R8/R13: VGPR 104-116, no spill);
// (512,4) and (1024,4) both flipped to the 64-reg bucket and spilled ~500 MB.
__global__ __launch_bounds__(512, 2)
void egcl_edge_kernel(const float* __restrict__ h, const float* __restrict__ coord,
                      const int* __restrict__ ei,
                      const unsigned short* __restrict__ fb,
                      const float* __restrict__ be1, const float* __restrict__ be2,
                      const unsigned short* __restrict__ Ws1s, const float* __restrict__ bs1,
                      const float* __restrict__ bs2, const float* __restrict__ bc1,
                      const float* __restrict__ Wc2,
                      int* __restrict__ cur, int* __restrict__ eidx,
                      unsigned short* __restrict__ efb_out, float* __restrict__ trans_out)
{
    __shared__ __attribute__((aligned(16))) float sm[SM_FLOATS];
    __shared__ int s_row[64], s_col[64];
    __shared__ float s_cd[192], s_rad[64];

    const int t = threadIdx.x;
    const int e0 = blockIdx.x * 64;    // 313 blocks; last block: 48 valid edges
    const int l = t & 63, w = t >> 6;
    const int kg = l >> 4;
    const int akoff = kg * 16;
    // MLP tiling: wave w owns row-tile (w&3), col-tiles (w>>2) and (w>>2)+2
    const int mrow = (w & 3) * 16;
    const int arow = mrow + (l & 15);
    const int orow = mrow + (kg << 2);
    const int cA = w >> 2;

    if (t < 64) {
        const int eid = min(e0 + t, EE - 1);
        const int r = ei[eid], c = ei[EE + eid];
        s_row[t] = r; s_col[t] = c;
        const float dx = coord[r*3+0] - coord[c*3+0];
        const float dy = coord[r*3+1] - coord[c*3+1];
        const float dz = coord[r*3+2] - coord[c*3+2];
        s_cd[t] = dx; s_cd[64+t] = dy; s_cd[128+t] = dz;
        s_rad[t] = dx*dx + dy*dy + dz*dz;
        // fused CSR fill (scan_csr ran before this kernel; node runs after)
        if (e0 + t < EE) {
            const int p = atomicAdd(&cur[r], 1);
            eidx[p] = e0 + t;
        }
    }
    __syncthreads();

    // P1: gather A_in bf16 [64 e][160k pad->336B] = [h_row(64), h_col(64), radial, 0]
    {
        const int ee = t >> 3, fg8 = t & 7;
        const int r = s_row[ee], c = s_col[ee];
        short8 fr, fc;
        #pragma unroll
        for (int u = 0; u < 8; ++u) fr[u] = (short)f2bf(h[(size_t)r*64 + fg8*8 + u]);
        #pragma unroll
        for (int u = 0; u < 8; ++u) fc[u] = (short)f2bf(h[(size_t)c*64 + fg8*8 + u]);
        *(short8*)((char*)sm + AIN_B + ee*336 + fg8*16)       = fr;
        *(short8*)((char*)sm + AIN_B + ee*336 + (8+fg8)*16)   = fc;
        if (fg8 < 5) {
            short8 z = {0,0,0,0,0,0,0,0};
            if (fg8 == 0) z[0] = (short)f2bf(s_rad[ee]);
            *(short8*)((char*)sm + AIN_B + ee*336 + (16 + fg8)*16) = z;
        }
    }
    __syncthreads();

    // P2: e1 = silu(in @ We1 + be1) (MFMA, K=160; B-frags direct from L2) -> E1A bf16
    {
        short8 a2[5];
        #pragma unroll
        for (int s = 0; s < 5; ++s)
            a2[s] = *(const short8*)((const char*)sm + AIN_B + arow*336 + s*64 + akoff);
        const short8* Bf = (const short8*)(fb + FB_WE1);
        #pragma unroll
        for (int tt = 0; tt < 2; ++tt) {
            const int tn = cA + tt*2;
            f32x4 acc = {0.f, 0.f, 0.f, 0.f};
            #pragma unroll
            for (int s = 0; s < 5; ++s)
                acc = __builtin_amdgcn_mfma_f32_16x16x32_bf16(a2[s], Bf[(s*4 + tn)*64 + l], acc, 0, 0, 0);
            const int col = tn*16 + (l & 15);
            const float bb = be1[col];
            #pragma unroll
            for (int r = 0; r < 4; ++r)
                *(unsigned short*)((char*)sm + E1A_B + (orow + r)*144 + col*2)
                    = f2bf(siluf(acc[r] + bb));
        }
    }
    __syncthreads();

    // P3: g = silu(e1 @ We2 + be2) (MFMA, K=64) -> GF32 f32 [i][72] + GA bf16 A-form
    {
        short8 a3[2];
        #pragma unroll
        for (int s = 0; s < 2; ++s)
            a3[s] = *(const short8*)((const char*)sm + E1A_B + arow*144 + s*64 + akoff);
        const short8* Bf = (const short8*)(fb + FB_WE2);
        #pragma unroll
        for (int tt = 0; tt < 2; ++tt) {
            const int tn = cA + tt*2;
            f32x4 acc = {0.f, 0.f, 0.f, 0.f};
            #pragma unroll
            for (int s = 0; s < 2; ++s)
                acc = __builtin_amdgcn_mfma_f32_16x16x32_bf16(a3[s], Bf[(s*4 + tn)*64 + l], acc, 0, 0, 0);
            const int col = tn*16 + (l & 15);
            const float bb = be2[col];
            #pragma unroll
            for (int r = 0; r < 4; ++r) {
                const float sv = siluf(acc[r] + bb);
                sm[GF32_F + col*72 + orow + r] = sv;
                *(unsigned short*)((char*)sm + GA_B + (orow + r)*144 + col*2) = f2bf(sv);
            }
        }
    }
    __syncthreads();

    // P4: SO3 GEMM acc[e,k] = sum_i g[e,i]*(g_bf16[e,:] @ 64*Ws1_i[:,k])
    // Wave w owns cols [w*16,+16) x 64 edges. B: L2 -> registers, 2 banks x 4 steps,
    // compiler-counted vmcnt, zero barriers. NEW: per-wave-contiguous Ws1s layout —
    // each wave streams a private sequential 128KB run (consecutive loads 1KB apart)
    // instead of a 1KB-per-8KB strided comb; grot phase rotation kept (harmless).
    const int grot = blockIdx.x & 31;

    short8 A[4][2];
    #pragma unroll
    for (int et = 0; et < 4; ++et)
        #pragma unroll
        for (int kh = 0; kh < 2; ++kh)
            A[et][kh] = *(const short8*)((const char*)sm + GA_B +
                                         (et*16 + (l & 15))*144 + kh*64 + kg*16);

    float accv[4][4];
    #pragma unroll
    for (int et = 0; et < 4; ++et)
        #pragma unroll
        for (int r = 0; r < 4; ++r) accv[et][r] = 0.0f;

    {
        const short8* Bp = (const short8*)Ws1s;   // frag for (wave w, step s): Bp[(w*128 + s)*64 + l]
        short8 q0[4], q1[4];

#define LOADBANK(P, G) { \
    const int GG_ = ((G) + grot) & 31; \
    _Pragma("unroll") \
    for (int j = 0; j < 4; ++j) P[j] = Bp[((w*128 + GG_*4 + j)*64 + l)]; \
    __builtin_amdgcn_sched_barrier(0); }
#define USEBANK(P, G) { \
    const int GU_ = ((G) + grot) & 31; \
    _Pragma("unroll") \
    for (int ii = 0; ii < 2; ++ii) { \
        const int i_ = 2*GU_ + ii; \
        _Pragma("unroll") \
        for (int et = 0; et < 4; ++et) { \
            f32x4 c = __builtin_amdgcn_mfma_f32_16x16x32_bf16(A[et][0], P[2*ii], (f32x4){0.f,0.f,0.f,0.f}, 0, 0, 0); \
            c = __builtin_amdgcn_mfma_f32_16x16x32_bf16(A[et][1], P[2*ii+1], c, 0, 0, 0); \
            const f32x4 g4 = *(const f32x4*)&sm[GF32_F + i_*72 + et*16 + (kg << 2)]; \
            _Pragma("unroll") \
            for (int r = 0; r < 4; ++r) accv[et][r] = fmaf(g4[r], c[r], accv[et][r]); \
        } \
    } }

        LOADBANK(q0, 0)
        LOADBANK(q1, 1)
        #pragma unroll 1
        for (int m = 0; m < 15; ++m) {
            USEBANK(q0, 2*m)     LOADBANK(q0, 2*m + 2)
            USEBANK(q1, 2*m + 1) LOADBANK(q1, 2*m + 3)
        }
        USEBANK(q0, 30)
        USEBANK(q1, 31)
#undef LOADBANK
#undef USEBANK
    }

    // t1 = relu(acc + bs1) -> T1A bf16 A-form [64 e][128 k] (over dead A_in)
    {
        const int kcol = w*16 + (l & 15);
        const float bk = bs1[kcol];
        #pragma unroll
        for (int et = 0; et < 4; ++et)
            #pragma unroll
            for (int r = 0; r < 4; ++r)
                *(unsigned short*)((char*)sm + T1A_B + (et*16 + (kg<<2) + r)*272 + kcol*2)
                    = f2bf(fmaxf(accv[et][r] + bk, 0.0f));
    }
    __syncthreads();

    // P5: ef = t1 @ Ws2 + bs2 (MFMA, K=128) -> global efb (bf16, guarded) + EFA bf16
    {
        short8 a5[4];
        #pragma unroll
        for (int s = 0; s < 4; ++s)
            a5[s] = *(const short8*)((const char*)sm + T1A_B + arow*272 + s*64 + akoff);
        const short8* Bf = (const short8*)(fb + FB_WS2);
        #pragma unroll
        for (int tt = 0; tt < 2; ++tt) {
            const int tn = cA + tt*2;
            f32x4 acc = {0.f, 0.f, 0.f, 0.f};
            #pragma unroll
            for (int s = 0; s < 4; ++s)
                acc = __builtin_amdgcn_mfma_f32_16x16x32_bf16(a5[s], Bf[(s*4 + tn)*64 + l], acc, 0, 0, 0);
            const int col = tn*16 + (l & 15);
            const float bb = bs2[col];
            #pragma unroll
            for (int r = 0; r < 4; ++r) {
                const unsigned short bv = f2bf(acc[r] + bb);
                if (e0 + orow + r < EE)
                    efb_out[(size_t)(e0 + orow + r)*64 + col] = bv;
                *(unsigned short*)((char*)sm + EFA_B + (orow + r)*144 + col*2) = bv;
            }
        }
    }
    __syncthreads();

    // P6: v = silu(ef @ Wc1 + bc1) (MFMA, K=64) -> V f32 (over dead GF32)
    {
        short8 a6[2];
        #pragma unroll
        for (int s = 0; s < 2; ++s)
            a6[s] = *(const short8*)((const char*)sm + EFA_B + arow*144 + s*64 + akoff);
        const short8* Bf = (const short8*)(fb + FB_WC1);
        #pragma unroll
        for (int tt = 0; tt < 2; ++tt) {
            const int tn = cA + tt*2;
            f32x4 acc = {0.f, 0.f, 0.f, 0.f};
            #pragma unroll
            for (int s = 0; s < 2; ++s)
                acc = __builtin_amdgcn_mfma_f32_16x16x32_bf16(a6[s], Bf[(s*4 + tn)*64 + l], acc, 0, 0, 0);
            const int col = tn*16 + (l & 15);
            const float bb = bc1[col];
            #pragma unroll
            for (int r = 0; r < 4; ++r)
                sm[GF32_F + col*72 + orow + r] = siluf(acc[r] + bb);
        }
    }
    __syncthreads();

    // P7: cw = v . Wc2 -> trans (guarded)
    if (t < 64 && e0 + t < EE) {
        float cw = 0.0f;
        for (int f = 0; f < 64; ++f) cw = fmaf(sm[GF32_F + f*72 + t], Wc2[f], cw);
        const int eid = e0 + t;
        trans_out[eid*3 + 0] = s_cd[t]     * cw;
        trans_out[eid*3 + 1] = s_cd[64+t]  * cw;
        trans_out[eid*3 + 2] = s_cd[128+t] * cw;
    }
}

__global__ __launch_bounds__(512, 2)
void egcl_node_kernel(const float* __restrict__ h, const float* __restrict__ coord,
                      const int* __restrict__ ei,
                      const unsigned short* __restrict__ fb,
                      const float* __restrict__ bn1, const float* __restrict__ bn2,
                      const unsigned short* __restrict__ efb, const float* __restrict__ trans,
                      const int* __restrict__ off, const int* __restrict__ eidx,
                      float* __restrict__ out)
{
    __shared__ __attribute__((aligned(16))) float smn[NSM_FLOATS];
    const int t = threadIdx.x;
    const int n0 = blockIdx.x * 32;
    const int l = t & 63, w = t >> 6;
    const int mt = w & 1, tn4 = w >> 1;
    const int kg = l >> 4;
    const int arow = mt * 16 + (l & 15);
    const int akoff = kg * 16;
    const int orow = mt * 16 + (kg << 2);
    const int col = tn4 * 16 + (l & 15);

    // N1 gather: m = [h(64), rel(3), agg(64), 0-pad] bf16 A-form + h_pos f32
    {
        const int nd = t >> 4, fg = t & 15;
        const int gn = n0 + nd;
        const f32x4 hv = *(const f32x4*)&h[(size_t)gn*64 + fg*4];
        #pragma unroll
        for (int u = 0; u < 4; ++u) {
            smn[NHP_F + nd*68 + fg*4 + u] = hv[u];
            *(unsigned short*)((char*)smn + NMA_B + nd*336 + (fg*4+u)*2) = f2bf(hv[u]);
        }
        const int o0 = off[gn], o1 = off[gn + 1];
        float acc[4] = {0.f, 0.f, 0.f, 0.f};
        for (int j = o0; j < o1; ++j) {
            const int e2 = eidx[j];
            const unsigned short* ep = &efb[(size_t)e2*64 + fg*4];
            #pragma unroll
            for (int u = 0; u < 4; ++u) acc[u] += bf2f(ep[u]);
        }
        #pragma unroll
        for (int u = 0; u < 4; ++u)
            *(unsigned short*)((char*)smn + NMA_B + nd*336 + (67+fg*4+u)*2) = f2bf(acc[u]);
    }
    if (t < 32) {
        const int gn = n0 + t;
        const int r = ei[gn], c = ei[EE + gn];   // rel for node n comes from edge n (E==N)
        const float dx = coord[r*3+0] - coord[c*3+0];
        const float dy = coord[r*3+1] - coord[c*3+1];
        const float dz = coord[r*3+2] - coord[c*3+2];
        const float inv = 1.0f / (sqrtf(dx*dx + dy*dy + dz*dz) + 1e-8f);
        const float rl[3] = {dx*inv, dy*inv, dz*inv};
        #pragma unroll
        for (int k = 0; k < 3; ++k) {
            smn[NHP_F + t*68 + 64 + k] = rl[k];
            *(unsigned short*)((char*)smn + NMA_B + t*336 + (64+k)*2) = f2bf(rl[k]);
        }
        #pragma unroll
        for (int cz = 131; cz < 136; ++cz)
            *(unsigned short*)((char*)smn + NMA_B + t*336 + cz*2) = 0;
        const short8 z8 = {0,0,0,0,0,0,0,0};
        #pragma unroll
        for (int ch = 17; ch < 20; ++ch)
            *(short8*)((char*)smn + NMA_B + t*336 + ch*16) = z8;
        const int o0 = off[gn], o1 = off[gn + 1];
        float nx = 0.f, ny = 0.f, nz = 0.f;
        for (int j = o0; j < o1; ++j) {
            const int e2 = eidx[j];
            nx += trans[e2*3 + 0];
            ny += trans[e2*3 + 1];
            nz += trans[e2*3 + 2];
        }
        const float cnt = fmaxf((float)(o1 - o0), 1.0f);
        out[NN*67 + gn*3 + 0] = coord[gn*3 + 0] + nx / cnt;
        out[NN*67 + gn*3 + 1] = coord[gn*3 + 1] + ny / cnt;
        out[NN*67 + gn*3 + 2] = coord[gn*3 + 2] + nz / cnt;
    }
    __syncthreads();

    // N2: z = silu(m @ Wn1 + bn1) (MFMA, K=160; B direct from L2) -> NZA bf16
    {
        const short8* Bf = (const short8*)(fb + FB_WN1);
        f32x4 acc = {0.f, 0.f, 0.f, 0.f};
        #pragma unroll
        for (int s = 0; s < 5; ++s) {
            const short8 a = *(const short8*)((const char*)smn + NMA_B + arow*336 + s*64 + akoff);
            acc = __builtin_amdgcn_mfma_f32_16x16x32_bf16(a, Bf[(s*4 + tn4)*64 + l], acc, 0, 0, 0);
        }
        const float bb = bn1[col];
        #pragma unroll
        for (int r = 0; r < 4; ++r)
            *(unsigned short*)((char*)smn + NZA_B + (orow + r)*144 + col*2)
                = f2bf(siluf(acc[r] + bb));
    }
    __syncthreads();

    // N3: h_out = h_pos + z @ Wn2 + bn2  (10 tiles of 16 cols over 8 waves; B from L2)
    for (int tid = w; tid < 10; tid += 8) {
        const int mtN = tid & 1, tnN = tid >> 1;
        const short8* Bf = (const short8*)(fb + FB_WN2);
        f32x4 acc = {0.f, 0.f, 0.f, 0.f};
        #pragma unroll
        for (int s = 0; s < 2; ++s) {
            const short8 a = *(const short8*)((const char*)smn + NZA_B + (mtN*16 + (l & 15))*144 + s*64 + akoff);
            acc = __builtin_amdgcn_mfma_f32_16x16x32_bf16(a, Bf[(s*5 + tnN)*64 + l], acc, 0, 0, 0);
        }
        const int colN = tnN*16 + (l & 15);
        if (colN < 67) {
            const float bb = bn2[colN];
            #pragma unroll
            for (int r = 0; r < 4; ++r) {
                const int row = mtN*16 + (kg << 2) + r;
                out[(size_t)(n0 + row)*67 + colN] = smn[NHP_F + row*68 + colN] + acc[r] + bb;
            }
        }
    }
}

extern "C" void kernel_launch(void* const* d_in, const int* in_sizes, int n_in,
                              void* d_out, int out_size, void* d_ws, size_t ws_size,
                              hipStream_t stream)
{
    (void)in_sizes; (void)n_in; (void)out_size; (void)ws_size;
    const float* h     = (const float*)d_in[0];
    const float* coord = (const float*)d_in[1];
    const int*   ei    = (const int*)d_in[2];
    const float* We1   = (const float*)d_in[3];
    const float* be1   = (const float*)d_in[4];
    const float* We2   = (const float*)d_in[5];
    const float* be2   = (const float*)d_in[6];
    const float* Ws1   = (const float*)d_in[7];
    const float* bs1   = (const float*)d_in[8];
    const float* Ws2   = (const float*)d_in[9];
    const float* bs2   = (const float*)d_in[10];
    const float* Wc1   = (const float*)d_in[11];
    const float* bc1   = (const float*)d_in[12];
    const float* Wc2   = (const float*)d_in[13];
    const float* Wn1   = (const float*)d_in[14];
    const float* bn1   = (const float*)d_in[15];
    const float* Wn2   = (const float*)d_in[16];
    const float* bn2   = (const float*)d_in[17];
    float* ws  = (float*)d_ws;
    float* out = (float*)d_out;

    unsigned short* efb = (unsigned short*)(ws + WS_EFB);
    float* trans = ws + WS_TRANS;
    int* cnti = (int*)(ws + WS_CNTI);
    int* off  = (int*)(ws + WS_OFF);
    int* cur  = (int*)(ws + WS_CUR);
    int* eidx = (int*)(ws + WS_EIDX);
    unsigned short* ws1s = (unsigned short*)(ws + WS_AL);
    unsigned short* fbb  = ws1s + WS1S_ELEMS;

    hipMemsetAsync((void*)cnti, 0, (size_t)NN * sizeof(int), stream);
    prep_all<<<277 + (EE + 255)/256, 256, 0, stream>>>(Ws1, We1, We2, Ws2, Wc1, Wn1, Wn2,
                                                       ws1s, fbb, ei, cnti);
    scan_csr<<<1, 1024, 0, stream>>>(cnti, off, cur);
    egcl_edge_kernel<<<(EE + 63)/64, 512, 0, stream>>>(h, coord, ei, fbb, be1, be2,
                                                       ws1s, bs1, bs2, bc1, Wc2,
                                                       cur, eidx, efb, trans);
    egcl_node_kernel<<<NN/32, 512, 0, stream>>>(h, coord, ei, fbb, bn1, bn2,
                                                efb, trans, off, eidx, out);
}

// Round 18
// 76.612 us; speedup vs baseline: 3.3629x; 1.1855x over previous
//
#include <hip/hip_runtime.h>

#define NN 20000
#define EE 20000

typedef __attribute__((ext_vector_type(8))) short short8;
typedef __attribute__((ext_vector_type(4))) float f32x4;

// workspace layout (float indices)
#define WS_EFB    0                         // edge_feat bf16 [E][64] = 640000 f32 units
#define WS_TRANS  640000                    // trans f32 [E][3]
#define WS_CNTI   700000                    // int cnt[N]
#define WS_OFF    720000                    // int off[N+1]
#define WS_CUR    740001                    // int cursor[N]
#define WS_EIDX   760001                    // int eidx[E]
#define WS_CORE_END 780001
#define WS_AL     ((WS_CORE_END + 3) & ~3)
#define WS1S_ELEMS (4096*128)               // bf16: swizzled 64*Ws1 (1 MB)
// MLP weight fragment buffers (bf16 elems)
#define FB_WE1 0        // K=129->160, 5 steps : 10240
#define FB_WE2 10240    // K=64, 2 steps       : 4096
#define FB_WS2 14336    // K=128, 4 steps      : 8192
#define FB_WC1 22528    // K=64, 2 steps       : 4096
#define FB_WN1 26624    // K=131->160, 5 steps : 10240
#define FB_WN2 36864    // K=64, 2 steps, 5 tn : 5120
#define FB_ELEMS 41984

// edge-kernel LDS (f32 indices) — 80-edge / 512-thread blocks, grid = 250 = 1/CU
#define AIN_B   0        // A_in bf16 [80][336B] = 6720 f32 ; later T1A bf16 [80][272B] (5440)
#define E1A_F   6720     // e1 / ef bf16 A-form [80][144B] = 2880 f32
#define GF32_F  9600     // g f32 [64 i][88] = 5632 ; later v f32
#define GA_F    15232    // g bf16 A-form [80][144B] = 2880 f32
#define SM_FLOATS 18112  // 72.4 KB
#define T1A_B   0
#define E1A_B   (E1A_F*4)
#define EFA_B   (E1A_F*4)
#define GA_B    (GA_F*4)

// node-kernel LDS (f32 indices) — weights read direct from L2 (no staging)
#define NMA_B   0        // m bf16 [32][336B] = 2688 f32
#define NHP_F   2688     // h_pos f32 [32][68] = 2176
#define NZA_F   4864     // z bf16 A-form [32][144B] = 1152 f32
#define NSM_FLOATS 6016  // 24.1 KB
#define NZA_B   (NZA_F*4)

__device__ __forceinline__ float siluf(float x) {
    return x * (1.0f / (1.0f + __expf(-x)));
}
__device__ __forceinline__ unsigned short f2bf(float f) {
    union { float f; unsigned u; } v; v.f = f;
    return (unsigned short)((v.u + 0x7FFF + ((v.u >> 16) & 1)) >> 16);
}
__device__ __forceinline__ float bf2f(unsigned short x) {
    union { unsigned u; float f; } v; v.u = ((unsigned)x) << 16; return v.f;
}

// ---------- CSR scan (fill is fused into the edge kernel) ----------
__global__ void scan_csr(const int* __restrict__ cnt, int* __restrict__ off,
                         int* __restrict__ cursor) {
    const int t = threadIdx.x;        // 1024 threads, 20 items each
    __shared__ int ps[1024];
    int loc[20];
    int s = 0;
    const int base = t * 20;
    #pragma unroll
    for (int k = 0; k < 20; ++k) {
        const int i = base + k;
        const int c = (i < NN) ? cnt[i] : 0;
        loc[k] = s; s += c;
    }
    ps[t] = s;
    __syncthreads();
    for (int d = 1; d < 1024; d <<= 1) {
        const int v = (t >= d) ? ps[t - d] : 0;
        __syncthreads();
        ps[t] += v;
        __syncthreads();
    }
    const int excl = ps[t] - s;
    #pragma unroll
    for (int k = 0; k < 20; ++k) {
        const int i = base + k;
        if (i < NN) { const int v = excl + loc[k]; off[i] = v; cursor[i] = v; }
    }
    if (t == 1023) off[NN] = ps[1023];
}

// ---------- combined prep: SO3 B swizzle + all MLP frag buffers + degree histogram ----------
__global__ void prep_all(const float* __restrict__ Ws1,
                         const float* __restrict__ We1, const float* __restrict__ We2,
                         const float* __restrict__ Ws2, const float* __restrict__ Wc1,
                         const float* __restrict__ Wn1, const float* __restrict__ Wn2,
                         unsigned short* __restrict__ ws1s, unsigned short* __restrict__ fbb,
                         const int* __restrict__ ei, int* __restrict__ cnt)
{
    const int b = blockIdx.x, t = threadIdx.x;
    if (b < 256) {
        // PER-WAVE-CONTIGUOUS layout: frag for (wave tn, step s) at ((tn*128+s)*64+l).
        // Value mapping: bf16(64*Ws1[(s*32 + 8*(l>>4) + u)][tn*16 + (l&15)])
        const int tid = b * 256 + t;
        const int l = tid & 63, fid = tid >> 6;
        const int s = fid >> 3, tn = fid & 7;
        const int krow = s * 32 + 8 * (l >> 4);
        const int ncol = tn * 16 + (l & 15);
        short8 frag;
        #pragma unroll
        for (int u = 0; u < 8; ++u)
            frag[u] = (short)f2bf(64.0f * Ws1[(krow + u) * 128 + ncol]);
        *(short8*)&ws1s[(size_t)((tn * 128 + s) * 64 + l) * 8] = frag;
    } else if (b < 277) {
        const int idx = (b - 256) * 256 + t;   // 0..5375, valid < 5248
        if (idx < 5248) {
            const float* W; int K, NC, NTN; unsigned short* dst; int local;
            if (idx < 1280)      { W = We1; K = 129; NC = 64; NTN = 4; dst = fbb + FB_WE1; local = idx; }
            else if (idx < 1792) { W = We2; K = 64;  NC = 64; NTN = 4; dst = fbb + FB_WE2; local = idx - 1280; }
            else if (idx < 2816) { W = Ws2; K = 128; NC = 64; NTN = 4; dst = fbb + FB_WS2; local = idx - 1792; }
            else if (idx < 3328) { W = Wc1; K = 64;  NC = 64; NTN = 4; dst = fbb + FB_WC1; local = idx - 2816; }
            else if (idx < 4608) { W = Wn1; K = 131; NC = 64; NTN = 4; dst = fbb + FB_WN1; local = idx - 3328; }
            else                 { W = Wn2; K = 64;  NC = 67; NTN = 5; dst = fbb + FB_WN2; local = idx - 4608; }
            const int per = NTN * 64;
            const int s = local / per, rem = local % per, tn = rem >> 6, ll = rem & 63;
            const int ccol = tn * 16 + (ll & 15), kr0 = s * 32 + 8 * (ll >> 4);
            short8 frag;
            #pragma unroll
            for (int u = 0; u < 8; ++u) {
                const int kr = kr0 + u;
                frag[u] = (kr < K && ccol < NC) ? (short)f2bf(W[kr * NC + ccol]) : (short)0;
            }
            *(short8*)&dst[local * 8] = frag;
        }
    } else {
        const int e = (b - 277) * 256 + t;
        if (e < EE) atomicAdd(&cnt[ei[e]], 1);
    }
}

// 80 edges/block, 512 threads, grid = 250 (= 1 block/CU, no residency imbalance,
// no tail). __launch_bounds__(512, 2) kept: the ONLY pair the allocator honors
// with a ~110-reg budget; (512,4)/(1024,4) flipped to 64-reg bucket and spilled.
__global__ __launch_bounds__(512, 2)
void egcl_edge_kernel(const float* __restrict__ h, const float* __restrict__ coord,
                      const int* __restrict__ ei,
                      const unsigned short* __restrict__ fb,
                      const float* __restrict__ be1, const float* __restrict__ be2,
                      const unsigned short* __restrict__ Ws1s, const float* __restrict__ bs1,
                      const float* __restrict__ bs2, const float* __restrict__ bc1,
                      const float* __restrict__ Wc2,
                      int* __restrict__ cur, int* __restrict__ eidx,
                      unsigned short* __restrict__ efb_out, float* __restrict__ trans_out)
{
    __shared__ __attribute__((aligned(16))) float sm[SM_FLOATS];
    __shared__ int s_row[80], s_col[80];
    __shared__ float s_cd[240], s_rad[80];

    const int t = threadIdx.x;
    const int e0 = blockIdx.x * 80;    // 250 * 80 == 20000 exactly
    const int l = t & 63, w = t >> 6;
    const int kg = l >> 4;
    const int akoff = kg * 16;

    if (t < 80) {
        const int eid = e0 + t;
        const int r = ei[eid], c = ei[EE + eid];
        s_row[t] = r; s_col[t] = c;
        const float dx = coord[r*3+0] - coord[c*3+0];
        const float dy = coord[r*3+1] - coord[c*3+1];
        const float dz = coord[r*3+2] - coord[c*3+2];
        s_cd[t] = dx; s_cd[80+t] = dy; s_cd[160+t] = dz;
        s_rad[t] = dx*dx + dy*dy + dz*dz;
        // fused CSR fill (scan_csr ran before this kernel; node runs after)
        const int p = atomicAdd(&cur[r], 1);
        eidx[p] = eid;
    }
    __syncthreads();

    // P1: gather A_in bf16 [80 e][160k pad->336B] = [h_row(64), h_col(64), radial, 0]
    {
        const int fg8 = t & 7;
        for (int ee = t >> 3; ee < 80; ee += 64) {
            const int r = s_row[ee], c = s_col[ee];
            short8 fr, fc;
            #pragma unroll
            for (int u = 0; u < 8; ++u) fr[u] = (short)f2bf(h[(size_t)r*64 + fg8*8 + u]);
            #pragma unroll
            for (int u = 0; u < 8; ++u) fc[u] = (short)f2bf(h[(size_t)c*64 + fg8*8 + u]);
            *(short8*)((char*)sm + AIN_B + ee*336 + fg8*16)     = fr;
            *(short8*)((char*)sm + AIN_B + ee*336 + (8+fg8)*16) = fc;
            if (fg8 < 5) {
                short8 z = {0,0,0,0,0,0,0,0};
                if (fg8 == 0) z[0] = (short)f2bf(s_rad[ee]);
                *(short8*)((char*)sm + AIN_B + ee*336 + (16 + fg8)*16) = z;
            }
        }
    }
    __syncthreads();

    // P2: e1 = silu(in @ We1 + be1) (MFMA, K=160) -> E1A bf16. 20 tiles (5 mr x 4 tn).
    for (int tile = w; tile < 20; tile += 8) {
        const int mr = tile >> 2, tn = tile & 3;
        const int ar = mr*16 + (l & 15), orw = mr*16 + (kg << 2), col = tn*16 + (l & 15);
        const short8* Bf = (const short8*)(fb + FB_WE1);
        f32x4 acc = {0.f, 0.f, 0.f, 0.f};
        #pragma unroll
        for (int s = 0; s < 5; ++s) {
            const short8 a = *(const short8*)((const char*)sm + AIN_B + ar*336 + s*64 + akoff);
            acc = __builtin_amdgcn_mfma_f32_16x16x32_bf16(a, Bf[(s*4 + tn)*64 + l], acc, 0, 0, 0);
        }
        const float bb = be1[col];
        #pragma unroll
        for (int r = 0; r < 4; ++r)
            *(unsigned short*)((char*)sm + E1A_B + (orw + r)*144 + col*2)
                = f2bf(siluf(acc[r] + bb));
    }
    __syncthreads();

    // P3: g = silu(e1 @ We2 + be2) (MFMA, K=64) -> GF32 f32 [i][88] + GA bf16 A-form
    for (int tile = w; tile < 20; tile += 8) {
        const int mr = tile >> 2, tn = tile & 3;
        const int ar = mr*16 + (l & 15), orw = mr*16 + (kg << 2), col = tn*16 + (l & 15);
        const short8* Bf = (const short8*)(fb + FB_WE2);
        f32x4 acc = {0.f, 0.f, 0.f, 0.f};
        #pragma unroll
        for (int s = 0; s < 2; ++s) {
            const short8 a = *(const short8*)((const char*)sm + E1A_B + ar*144 + s*64 + akoff);
            acc = __builtin_amdgcn_mfma_f32_16x16x32_bf16(a, Bf[(s*4 + tn)*64 + l], acc, 0, 0, 0);
        }
        const float bb = be2[col];
        #pragma unroll
        for (int r = 0; r < 4; ++r) {
            const float sv = siluf(acc[r] + bb);
            sm[GF32_F + col*88 + orw + r] = sv;
            *(unsigned short*)((char*)sm + GA_B + (orw + r)*144 + col*2) = f2bf(sv);
        }
    }
    __syncthreads();

    // P4: SO3 GEMM acc[e,k] = sum_i g[e,i]*(g_bf16[e,:] @ 64*Ws1_i[:,k])
    // Wave w owns cols [w*16,+16) x 80 edges (5 et tiles). B: L2 -> registers,
    // 2 banks x 4 steps, compiler-counted vmcnt, zero barriers.
    const int grot = blockIdx.x & 31;

    short8 A[5][2];
    #pragma unroll
    for (int et = 0; et < 5; ++et)
        #pragma unroll
        for (int kh = 0; kh < 2; ++kh)
            A[et][kh] = *(const short8*)((const char*)sm + GA_B +
                                         (et*16 + (l & 15))*144 + kh*64 + kg*16);

    f32x4 accv[5];
    #pragma unroll
    for (int et = 0; et < 5; ++et) accv[et] = (f32x4){0.f, 0.f, 0.f, 0.f};

    {
        const short8* Bp = (const short8*)Ws1s;   // frag for (wave w, step s): Bp[(w*128 + s)*64 + l]
        short8 q0[4], q1[4];

#define LOADBANK(P, G) { \
    const int GG_ = ((G) + grot) & 31; \
    _Pragma("unroll") \
    for (int j = 0; j < 4; ++j) P[j] = Bp[((w*128 + GG_*4 + j)*64 + l)]; \
    __builtin_amdgcn_sched_barrier(0); }
#define USEBANK(P, G) { \
    const int GU_ = ((G) + grot) & 31; \
    _Pragma("unroll") \
    for (int ii = 0; ii < 2; ++ii) { \
        const int i_ = 2*GU_ + ii; \
        _Pragma("unroll") \
        for (int et = 0; et < 5; ++et) { \
            f32x4 c = __builtin_amdgcn_mfma_f32_16x16x32_bf16(A[et][0], P[2*ii], (f32x4){0.f,0.f,0.f,0.f}, 0, 0, 0); \
            c = __builtin_amdgcn_mfma_f32_16x16x32_bf16(A[et][1], P[2*ii+1], c, 0, 0, 0); \
            const f32x4 g4 = *(const f32x4*)&sm[GF32_F + i_*88 + et*16 + (kg << 2)]; \
            _Pragma("unroll") \
            for (int r = 0; r < 4; ++r) accv[et][r] = fmaf(g4[r], c[r], accv[et][r]); \
        } \
    } }

        LOADBANK(q0, 0)
        LOADBANK(q1, 1)
        #pragma unroll 1
        for (int m = 0; m < 15; ++m) {
            USEBANK(q0, 2*m)     LOADBANK(q0, 2*m + 2)
            USEBANK(q1, 2*m + 1) LOADBANK(q1, 2*m + 3)
        }
        USEBANK(q0, 30)
        USEBANK(q1, 31)
#undef LOADBANK
#undef USEBANK
    }

    // t1 = relu(acc + bs1) -> T1A bf16 A-form [80 e][128 k] (over dead A_in)
    {
        const int kcol = w*16 + (l & 15);
        const float bk = bs1[kcol];
        #pragma unroll
        for (int et = 0; et < 5; ++et)
            #pragma unroll
            for (int r = 0; r < 4; ++r)
                *(unsigned short*)((char*)sm + T1A_B + (et*16 + (kg<<2) + r)*272 + kcol*2)
                    = f2bf(fmaxf(accv[et][r] + bk, 0.0f));
    }
    __syncthreads();

    // P5: ef = t1 @ Ws2 + bs2 (MFMA, K=128) -> global efb (bf16) + EFA bf16
    for (int tile = w; tile < 20; tile += 8) {
        const int mr = tile >> 2, tn = tile & 3;
        const int ar = mr*16 + (l & 15), orw = mr*16 + (kg << 2), col = tn*16 + (l & 15);
        const short8* Bf = (const short8*)(fb + FB_WS2);
        f32x4 acc = {0.f, 0.f, 0.f, 0.f};
        #pragma unroll
        for (int s = 0; s < 4; ++s) {
            const short8 a = *(const short8*)((const char*)sm + T1A_B + ar*272 + s*64 + akoff);
            acc = __builtin_amdgcn_mfma_f32_16x16x32_bf16(a, Bf[(s*4 + tn)*64 + l], acc, 0, 0, 0);
        }
        const float bb = bs2[col];
        #pragma unroll
        for (int r = 0; r < 4; ++r) {
            const unsigned short bv = f2bf(acc[r] + bb);
            efb_out[(size_t)(e0 + orw + r)*64 + col] = bv;
            *(unsigned short*)((char*)sm + EFA_B + (orw + r)*144 + col*2) = bv;
        }
    }
    __syncthreads();

    // P6: v = silu(ef @ Wc1 + bc1) (MFMA, K=64) -> V f32 (over dead GF32)
    for (int tile = w; tile < 20; tile += 8) {
        const int mr = tile >> 2, tn = tile & 3;
        const int ar = mr*16 + (l & 15), orw = mr*16 + (kg << 2), col = tn*16 + (l & 15);
        const short8* Bf = (const short8*)(fb + FB_WC1);
        f32x4 acc = {0.f, 0.f, 0.f, 0.f};
        #pragma unroll
        for (int s = 0; s < 2; ++s) {
            const short8 a = *(const short8*)((const char*)sm + EFA_B + ar*144 + s*64 + akoff);
            acc = __builtin_amdgcn_mfma_f32_16x16x32_bf16(a, Bf[(s*4 + tn)*64 + l], acc, 0, 0, 0);
        }
        const float bb = bc1[col];
        #pragma unroll
        for (int r = 0; r < 4; ++r)
            sm[GF32_F + col*88 + orw + r] = siluf(acc[r] + bb);
    }
    __syncthreads();

    // P7: cw = v . Wc2 -> trans
    if (t < 80) {
        float cw = 0.0f;
        for (int f = 0; f < 64; ++f) cw = fmaf(sm[GF32_F + f*88 + t], Wc2[f], cw);
        const int eid = e0 + t;
        trans_out[eid*3 + 0] = s_cd[t]     * cw;
        trans_out[eid*3 + 1] = s_cd[80+t]  * cw;
        trans_out[eid*3 + 2] = s_cd[160+t] * cw;
    }
}

__global__ __launch_bounds__(512, 2)
void egcl_node_kernel(const float* __restrict__ h, const float* __restrict__ coord,
                      const int* __restrict__ ei,
                      const unsigned short* __restrict__ fb,
                      const float* __restrict__ bn1, const float* __restrict__ bn2,
                      const unsigned short* __restrict__ efb, const float* __restrict__ trans,
                      const int* __restrict__ off, const int* __restrict__ eidx,
                      float* __restrict__ out)
{
    __shared__ __attribute__((aligned(16))) float smn[NSM_FLOATS];
    const int t = threadIdx.x;
    const int n0 = blockIdx.x * 32;
    const int l = t & 63, w = t >> 6;
    const int mt = w & 1, tn4 = w >> 1;
    const int kg = l >> 4;
    const int arow = mt * 16 + (l & 15);
    const int akoff = kg * 16;
    const int orow = mt * 16 + (kg << 2);
    const int col = tn4 * 16 + (l & 15);

    // N1 gather: m = [h(64), rel(3), agg(64), 0-pad] bf16 A-form + h_pos f32
    {
        const int nd = t >> 4, fg = t & 15;
        const int gn = n0 + nd;
        const f32x4 hv = *(const f32x4*)&h[(size_t)gn*64 + fg*4];
        #pragma unroll
        for (int u = 0; u < 4; ++u) {
            smn[NHP_F + nd*68 + fg*4 + u] = hv[u];
            *(unsigned short*)((char*)smn + NMA_B + nd*336 + (fg*4+u)*2) = f2bf(hv[u]);
        }
        const int o0 = off[gn], o1 = off[gn + 1];
        float acc[4] = {0.f, 0.f, 0.f, 0.f};
        for (int j = o0; j < o1; ++j) {
            const int e2 = eidx[j];
            const unsigned short* ep = &efb[(size_t)e2*64 + fg*4];
            #pragma unroll
            for (int u = 0; u < 4; ++u) acc[u] += bf2f(ep[u]);
        }
        #pragma unroll
        for (int u = 0; u < 4; ++u)
            *(unsigned short*)((char*)smn + NMA_B + nd*336 + (67+fg*4+u)*2) = f2bf(acc[u]);
    }
    if (t < 32) {
        const int gn = n0 + t;
        const int r = ei[gn], c = ei[EE + gn];   // rel for node n comes from edge n (E==N)
        const float dx = coord[r*3+0] - coord[c*3+0];
        const float dy = coord[r*3+1] - coord[c*3+1];
        const float dz = coord[r*3+2] - coord[c*3+2];
        const float inv = 1.0f / (sqrtf(dx*dx + dy*dy + dz*dz) + 1e-8f);
        const float rl[3] = {dx*inv, dy*inv, dz*inv};
        #pragma unroll
        for (int k = 0; k < 3; ++k) {
            smn[NHP_F + t*68 + 64 + k] = rl[k];
            *(unsigned short*)((char*)smn + NMA_B + t*336 + (64+k)*2) = f2bf(rl[k]);
        }
        #pragma unroll
        for (int cz = 131; cz < 136; ++cz)
            *(unsigned short*)((char*)smn + NMA_B + t*336 + cz*2) = 0;
        const short8 z8 = {0,0,0,0,0,0,0,0};
        #pragma unroll
        for (int ch = 17; ch < 20; ++ch)
            *(short8*)((char*)smn + NMA_B + t*336 + ch*16) = z8;
        const int o0 = off[gn], o1 = off[gn + 1];
        float nx = 0.f, ny = 0.f, nz = 0.f;
        for (int j = o0; j < o1; ++j) {
            const int e2 = eidx[j];
            nx += trans[e2*3 + 0];
            ny += trans[e2*3 + 1];
            nz += trans[e2*3 + 2];
        }
        const float cnt = fmaxf((float)(o1 - o0), 1.0f);
        out[NN*67 + gn*3 + 0] = coord[gn*3 + 0] + nx / cnt;
        out[NN*67 + gn*3 + 1] = coord[gn*3 + 1] + ny / cnt;
        out[NN*67 + gn*3 + 2] = coord[gn*3 + 2] + nz / cnt;
    }
    __syncthreads();

    // N2: z = silu(m @ Wn1 + bn1) (MFMA, K=160; B direct from L2) -> NZA bf16
    {
        const short8* Bf = (const short8*)(fb + FB_WN1);
        f32x4 acc = {0.f, 0.f, 0.f, 0.f};
        #pragma unroll
        for (int s = 0; s < 5; ++s) {
            const short8 a = *(const short8*)((const char*)smn + NMA_B + arow*336 + s*64 + akoff);
            acc = __builtin_amdgcn_mfma_f32_16x16x32_bf16(a, Bf[(s*4 + tn4)*64 + l], acc, 0, 0, 0);
        }
        const float bb = bn1[col];
        #pragma unroll
        for (int r = 0; r < 4; ++r)
            *(unsigned short*)((char*)smn + NZA_B + (orow + r)*144 + col*2)
                = f2bf(siluf(acc[r] + bb));
    }
    __syncthreads();

    // N3: h_out = h_pos + z @ Wn2 + bn2  (10 tiles of 16 cols over 8 waves; B from L2)
    for (int tid = w; tid < 10; tid += 8) {
        const int mtN = tid & 1, tnN = tid >> 1;
        const short8* Bf = (const short8*)(fb + FB_WN2);
        f32x4 acc = {0.f, 0.f, 0.f, 0.f};
        #pragma unroll
        for (int s = 0; s < 2; ++s) {
            const short8 a = *(const short8*)((const char*)smn + NZA_B + (mtN*16 + (l & 15))*144 + s*64 + akoff);
            acc = __builtin_amdgcn_mfma_f32_16x16x32_bf16(a, Bf[(s*5 + tnN)*64 + l], acc, 0, 0, 0);
        }
        const int colN = tnN*16 + (l & 15);
        if (colN < 67) {
            const float bb = bn2[colN];
            #pragma unroll
            for (int r = 0; r < 4; ++r) {
                const int row = mtN*16 + (kg << 2) + r;
                out[(size_t)(n0 + row)*67 + colN] = smn[NHP_F + row*68 + colN] + acc[r] + bb;
            }
        }
    }
}

extern "C" void kernel_launch(void* const* d_in, const int* in_sizes, int n_in,
                              void* d_out, int out_size, void* d_ws, size_t ws_size,
                              hipStream_t stream)
{
    (void)in_sizes; (void)n_in; (void)out_size; (void)ws_size;
    const float* h     = (const float*)d_in[0];
    const float* coord = (const float*)d_in[1];
    const int*   ei    = (const int*)d_in[2];
    const float* We1   = (const float*)d_in[3];
    const float* be1   = (const float*)d_in[4];
    const float* We2   = (const float*)d_in[5];
    const float* be2   = (const float*)d_in[6];
    const float* Ws1   = (const float*)d_in[7];
    const float* bs1   = (const float*)d_in[8];
    const float* Ws2   = (const float*)d_in[9];
    const float* bs2   = (const float*)d_in[10];
    const float* Wc1   = (const float*)d_in[11];
    const float* bc1   = (const float*)d_in[12];
    const float* Wc2   = (const float*)d_in[13];
    const float* Wn1   = (const float*)d_in[14];
    const float* bn1   = (const float*)d_in[15];
    const float* Wn2   = (const float*)d_in[16];
    const float* bn2   = (const float*)d_in[17];
    float* ws  = (float*)d_ws;
    float* out = (float*)d_out;

    unsigned short* efb = (unsigned short*)(ws + WS_EFB);
    float* trans = ws + WS_TRANS;
    int* cnti = (int*)(ws + WS_CNTI);
    int* off  = (int*)(ws + WS_OFF);
    int* cur  = (int*)(ws + WS_CUR);
    int* eidx = (int*)(ws + WS_EIDX);
    unsigned short* ws1s = (unsigned short*)(ws + WS_AL);
    unsigned short* fbb  = ws1s + WS1S_ELEMS;

    hipMemsetAsync((void*)cnti, 0, (size_t)NN * sizeof(int), stream);
    prep_all<<<277 + (EE + 255)/256, 256, 0, stream>>>(Ws1, We1, We2, Ws2, Wc1, Wn1, Wn2,
                                                       ws1s, fbb, ei, cnti);
    scan_csr<<<1, 1024, 0, stream>>>(cnti, off, cur);
    egcl_edge_kernel<<<EE/80, 512, 0, stream>>>(h, coord, ei, fbb, be1, be2,
                                                ws1s, bs1, bs2, bc1, Wc2,
                                                cur, eidx, efb, trans);
    egcl_node_kernel<<<NN/32, 512, 0, stream>>>(h, coord, ei, fbb, bn1, bn2,
                                                efb, trans, off, eidx, out);
}